// Round 9
// baseline (709.321 us; speedup 1.0000x reference)
//
#include <hip/hip_runtime.h>
#include <hip/hip_bf16.h>
#include <math.h>

#define NDIM 300
#define KPAD 320          // K padded: 300 x-dims + 3 normal dims + zeros
#define NREAL 1800
#define NPAD 1920         // 15 tiles of 128

typedef __hip_bfloat16 bf16;
typedef __attribute__((ext_vector_type(8))) short short8;   // 8 bf16 (4 VGPRs)
typedef __attribute__((ext_vector_type(4))) float f32x4;

__device__ __forceinline__ void gl_lds16(const void* g, void* l) {
    __builtin_amdgcn_global_load_lds(
        (const __attribute__((address_space(1))) void*)g,
        (__attribute__((address_space(3))) void*)l, 16, 0, 0);
}

__device__ __forceinline__ float bflo(uint u) { return __uint_as_float(u << 16); }
__device__ __forceinline__ float bfhi(uint u) { return __uint_as_float(u & 0xFFFF0000u); }

// ---------------- K1: small_pre U conv_xb U hist (independent parts) ----------------
// NOTE: Mxy and bgeo are pre-scaled by 2 (tanh argument doubling folded in).
__global__ void k1_pre_conv_hist(
    const float* __restrict__ Wn, const float* __restrict__ bn,
    const float* __restrict__ Wxy, const float* __restrict__ bxy,
    const float* __restrict__ Wloc, const float* __restrict__ bloc,
    const float* __restrict__ bobj,
    const float* __restrict__ Wfus,
    const float* __restrict__ vocab,
    float* __restrict__ Wn1, float* __restrict__ Wn2,
    float* __restrict__ Mxy, float* __restrict__ bgeo,
    float* __restrict__ vf5, float* __restrict__ t0, float* __restrict__ t1,
    const float* __restrict__ X, const float* __restrict__ Nrm,
    bf16* __restrict__ Xb, int M, int nconv,
    const int* __restrict__ ei, int* __restrict__ deg, int E)
{
    const int bid = blockIdx.x;
    if (bid < 19) {
        int i = bid * 256 + threadIdx.x;
        if (i < 900) {
            int r = i / 300, c = i % 300;
            float s = 0.f;
            for (int k = 0; k < 300; k++) s += Wn[r*300+k] * Wloc[(300+k)*300+c];
            Wn1[i] = s;
        } else if (i < 1800) {
            int j = i - 900; int r = j/300, c = j%300;
            float s = 0.f;
            for (int k = 0; k < 300; k++) s += Wn[r*300+k] * Wloc[(600+k)*300+c];
            Wn2[j] = s;
        } else if (i < 2400) {
            int j = i - 1800; int r = j/300, c = j%300;
            float s = 0.f;
            for (int k = 0; k < 300; k++) s += Wxy[r*300+k] * Wloc[k*300+c];
            Mxy[j] = 2.f * s;                           // x2 folded (tanh arg)
        } else if (i < 2700) {
            int c = i - 2400;
            float s = bloc[c] + bobj[c];
            for (int k = 0; k < 300; k++) s += bxy[k] * Wloc[k*300+c];
            for (int k = 0; k < 300; k++) s += bn[k] * (Wloc[(300+k)*300+c] + Wloc[(600+k)*300+c]);
            bgeo[c] = 2.f * s;                          // x2 folded (tanh arg)
        } else if (i < 4200) {
            int j = i - 2700; int p = j/300, c = j%300;
            float s = 0.f;
            for (int k = 0; k < 300; k++) s += vocab[(2+p)*300+k] * Wfus[(300+k)*300+c];
            vf5[j] = s;
        } else if (i < 4500) {
            int c = i - 4200;
            float s = 0.f;
            for (int k = 0; k < 300; k++) s += vocab[k] * Wfus[k*300+c];
            t0[c] = s;
        } else if (i < 4800) {
            int c = i - 4500;
            float s = 0.f;
            for (int k = 0; k < 300; k++) s += vocab[300+k] * Wfus[k*300+c];
            t1[c] = s;
        }
    } else if (bid < 19 + nconv) {
        int i = (bid - 19) * 256 + threadIdx.x;
        int row = i / 40, c8 = i % 40;
        if (row >= M) return;
        int c0 = c8 * 8;
        union { bf16 h[8]; short8 s; } u;
        #pragma unroll
        for (int t = 0; t < 8; t++) {
            int c = c0 + t;
            float v = 0.f;
            if (c < 300)      v = X[(size_t)row * 300 + c];
            else if (c < 303) v = Nrm[(size_t)row * 3 + (c - 300)];
            u.h[t] = __float2bfloat16(v);
        }
        *(short8*)&Xb[(size_t)row * 320 + c0] = u.s;
    } else {
        int e = (bid - 19 - nconv) * 256 + threadIdx.x;
        if (e < E) atomicAdd(&deg[ei[E + e]], 1);
    }
}

// ---------------- K2: small_pre2 U pack_w ----------------
// pack_w: OUTPUT COLUMNS PERMUTED so the gemm epilogue directly produces
// interleaved QP / PK layouts:
//   c' in [0,600):    even -> Q_{c'/2}   (seg0), odd -> Pi_{c'/2} (seg4, x2)
//   c' in [600,1200): even -> Pj         (seg5, x2), odd -> Kf    (seg1)
//   c' in [1200,1500): V (seg2);  [1500,1800): skip (seg3)
__global__ void k2_pre2_pack(
    const float* __restrict__ We, const float* __restrict__ bfus,
    const float* __restrict__ vf5, const float* __restrict__ t0, const float* __restrict__ t1,
    const float* __restrict__ Wcls,
    float* __restrict__ E8, float* __restrict__ WclsT,
    const float* __restrict__ Wq, const float* __restrict__ Wk,
    const float* __restrict__ Wv, const float* __restrict__ Wskip,
    const float* __restrict__ Wobj,
    const float* __restrict__ Wn1, const float* __restrict__ Wn2,
    const float* __restrict__ bq, const float* __restrict__ bk,
    const float* __restrict__ bv, const float* __restrict__ bskip,
    bf16* __restrict__ WcatT, float* __restrict__ bcat)
{
    const int bid = blockIdx.x;
    if (bid < 16) {
        int i = bid * 256 + threadIdx.x;
        if (i < 2400) {
            int r = i / 300, c = i % 300;
            const float* src;
            if (r == 0) src = t0;
            else if (r == 1) src = t1;
            else if (r == 7) src = bfus;
            else src = vf5 + (r - 2) * 300;
            float s = 0.f;
            for (int k = 0; k < 300; k++) s += src[k] * We[k*300+c];
            E8[i] = s;
        } else if (i < 3900) {
            int j = i - 2400; int cl = j / 300, c = j % 300;
            WclsT[cl * 300 + c] = Wcls[c * 5 + cl];
        }
    } else {
        int i = (bid - 16) * 256 + threadIdx.x;
        if (i < NREAL) {
            int c = i;
            float b = 0.f;
            if (c < 600)       { if (!(c & 1)) b = bq[c >> 1]; }
            else if (c < 1200) { int cc = c - 600; if (cc & 1) b = bk[cc >> 1]; }
            else if (c < 1500) b = bv[c - 1200];
            else               b = bskip[c - 1500];
            bcat[i] = b;
        }
        if (i < NPAD * KPAD) {
            int cp = i / KPAD, k = i % KPAD;
            float v = 0.f;
            if (cp < NREAL) {
                int seg, jj;
                if (cp < 600)       { jj = cp >> 1; seg = (cp & 1) ? 4 : 0; }
                else if (cp < 1200) { int cc = cp - 600; jj = cc >> 1; seg = (cc & 1) ? 1 : 5; }
                else if (cp < 1500) { jj = cp - 1200; seg = 2; }
                else                { jj = cp - 1500; seg = 3; }
                if (k < 300) {
                    switch (seg) {
                        case 0: v = Wq[k*300+jj]; break;
                        case 1: v = Wk[k*300+jj]; break;
                        case 2: v = Wv[k*300+jj]; break;
                        case 3: v = Wskip[k*300+jj]; break;
                        case 4: v = Wobj[k*300+jj] - Wobj[(300+k)*300+jj]; break;
                        default: v = Wobj[(300+k)*300+jj]; break;
                    }
                } else if (k < 303) {
                    if (seg == 4) v = Wn1[(k-300)*300+jj];
                    else if (seg == 5) v = Wn2[(k-300)*300+jj];
                }
                if (seg >= 4) v *= 2.f;                 // x2 folded (tanh arg)
            }
            WcatT[i] = __float2bfloat16(v);
        }
    }
}

// ---------------- scans ----------------
__global__ __launch_bounds__(1024) void scan_local(
    const int* __restrict__ deg, int* __restrict__ off, int* __restrict__ bsum, int N)
{
    __shared__ int buf[1024];
    int i = blockIdx.x * 1024 + threadIdx.x;
    int v = (i < N) ? deg[i] : 0;
    buf[threadIdx.x] = v;
    __syncthreads();
    #pragma unroll
    for (int ofs = 1; ofs < 1024; ofs <<= 1) {
        int t = (threadIdx.x >= ofs) ? buf[threadIdx.x - ofs] : 0;
        __syncthreads();
        buf[threadIdx.x] += t;
        __syncthreads();
    }
    if (i < N) off[i] = buf[threadIdx.x] - v;       // local exclusive
    if (threadIdx.x == 1023) bsum[blockIdx.x] = buf[1023];
}

__global__ __launch_bounds__(1024) void scan_bsum(
    const int* __restrict__ bsum, int* __restrict__ bexc, int nb)
{
    __shared__ int buf[1024];
    int v = (threadIdx.x < nb) ? bsum[threadIdx.x] : 0;
    buf[threadIdx.x] = v;
    __syncthreads();
    #pragma unroll
    for (int ofs = 1; ofs < 1024; ofs <<= 1) {
        int t = (threadIdx.x >= ofs) ? buf[threadIdx.x - ofs] : 0;
        __syncthreads();
        buf[threadIdx.x] += t;
        __syncthreads();
    }
    if (threadIdx.x < nb) bexc[threadIdx.x] = buf[threadIdx.x] - v;
}

__global__ void scan_add(int* __restrict__ off, int* __restrict__ cur,
                         const int* __restrict__ bexc, int N, int E)
{
    int i = blockIdx.x * blockDim.x + threadIdx.x;
    if (i < N) {
        int o = off[i] + bexc[i >> 10];
        off[i] = o; cur[i] = o;
    }
    if (i == 0) off[N] = E;
}

// ---------------- MFMA node-GEMM: [N,320]bf16 @ [320,1920]bf16 ----------------
// 1D grid, XCD-pinned panel mapping. Row-half LDS-transpose epilogue keeps total
// LDS = 32768 B. No forced min-occupancy (R6 lesson: launch_bounds(256,5) made the
// allocator spill the 64-VGPR accumulator -> +196 MB scratch traffic, 126->148us).
// Staging base pointers hoisted out of the K-loop to trim live registers.
__global__ __launch_bounds__(256) void gemm_mfma(
    const bf16* __restrict__ Xb,
    const bf16* __restrict__ Bt, const float* __restrict__ bcat,
    bf16* __restrict__ QP, bf16* __restrict__ PK, bf16* __restrict__ V,
    float* __restrict__ Ot, int M, int npan)
{
    __shared__ __align__(16) char smraw[32768];
    bf16*  Asb = (bf16*)smraw;                 // [2][128*32] staging
    bf16*  Bsb = (bf16*)(smraw + 16384);       // [2][128*32] staging
    bf16*  EP  = (bf16*)smraw;                 // [64][136] epilogue bf16 view (17408 B)
    float* EPf = (float*)smraw;                // [64][68]  epilogue f32 view  (17408 B)

    const int bid = blockIdx.x;
    int p, cx;
    {
        const int full = (npan >> 3) * 120;
        if (bid < full) {
            int g = bid / 120, r = bid - g * 120;
            p = (g << 3) + (r & 7); cx = r >> 3;
        } else {
            int r = bid - full;
            int tp = npan & 7;                  // >0 whenever this branch is taken
            p = (npan & ~7) + r % tp; cx = r / tp;
        }
    }
    const int r0 = p * 128;
    const int c0 = cx * 128;

    const int tid  = threadIdx.x;
    const int wave = tid >> 6;
    const int lane = tid & 63;
    const int wm = (wave >> 1) * 64;
    const int wn = (wave & 1) * 64;
    const int lr = lane & 15;
    const int lq = lane >> 4;

    f32x4 acc[4][4];
    #pragma unroll
    for (int j = 0; j < 4; j++)
        #pragma unroll
        for (int i = 0; i < 4; i++) acc[j][i] = (f32x4){0.f, 0.f, 0.f, 0.f};

    // hoisted per-thread staging sources (K-loop adds only kb)
    const bf16* aSrc[2];
    const bf16* bSrc[2];
    {
        const int bcol_l = lane >> 2;
        const int bkp    = (lane & 3) * 8;
        #pragma unroll
        for (int h = 0; h < 2; h++) {
            int t = h * 256 + wave * 64 + lane;
            int grow = min(r0 + (t >> 2), M - 1);
            aSrc[h] = Xb + (size_t)grow * 320 + (t & 3) * 8;
            bSrc[h] = Bt + (size_t)(c0 + wave * 32 + h * 16 + bcol_l) * KPAD + bkp;
        }
    }

    auto stage = [&](int buf, int kb) {
        #pragma unroll
        for (int h = 0; h < 2; h++) {
            int tbase = h * 256 + wave * 64;          // wave-uniform LDS base
            gl_lds16(aSrc[h] + kb, &Asb[buf * 4096 + tbase * 8]);
        }
        #pragma unroll
        for (int h = 0; h < 2; h++) {
            int cloc = wave * 32 + h * 16;
            gl_lds16(bSrc[h] + kb, &Bsb[buf * 4096 + cloc * 32]);
        }
    };

    stage(0, 0);
    #pragma unroll
    for (int it = 0; it < 10; it++) {
        __syncthreads();
        if (it < 9) stage((it + 1) & 1, (it + 1) * 32);
        const int b = it & 1;
        short8 af[4], bfr[4];
        #pragma unroll
        for (int i = 0; i < 4; i++)
            af[i] = *(const short8*)&Asb[b * 4096 + (wm + i * 16 + lr) * 32 + lq * 8];
        #pragma unroll
        for (int j = 0; j < 4; j++)
            bfr[j] = *(const short8*)&Bsb[b * 4096 + (wn + j * 16 + lr) * 32 + lq * 8];
        #pragma unroll
        for (int j = 0; j < 4; j++)
            #pragma unroll
            for (int i = 0; i < 4; i++)
                acc[j][i] = __builtin_amdgcn_mfma_f32_16x16x32_bf16(
                    bfr[j], af[i], acc[j][i], 0, 0, 0);
    }

    // ---------------- epilogue: row-half LDS transposes, coalesced stores ----------------
    // pass 1: bf16 destinations (cols < 1500), two 64-row halves
    if (c0 < 1500) {
        #pragma unroll
        for (int hm = 0; hm < 2; hm++) {
            __syncthreads();                    // LDS region free (staging or prev half)
            if ((wave >> 1) == hm) {            // this wave-pair owns rows hm*64..+63
                #pragma unroll
                for (int j = 0; j < 4; j++) {
                    int colL = wn + j * 16 + lq * 4;
                    float4 bb = *(const float4*)&bcat[c0 + colL];
                    #pragma unroll
                    for (int i = 0; i < 4; i++) {
                        int row = i * 16 + lr;          // local 0..63
                        union { bf16 h[4]; uint2 u2; } pk;
                        pk.h[0] = __float2bfloat16(acc[j][i][0] + bb.x);
                        pk.h[1] = __float2bfloat16(acc[j][i][1] + bb.y);
                        pk.h[2] = __float2bfloat16(acc[j][i][2] + bb.z);
                        pk.h[3] = __float2bfloat16(acc[j][i][3] + bb.w);
                        *(uint2*)&EP[row * 136 + colL] = pk.u2;
                    }
                }
            }
            __syncthreads();
            #pragma unroll
            for (int rep = 0; rep < 8; rep++) {
                int row = wave * 16 + rep * 2 + (lane >> 5);    // local 0..63
                int gr = r0 + hm * 64 + row;
                int col = c0 + 4 * (lane & 31);
                if (gr < M && col < 1500) {
                    uint2 val = *(const uint2*)&EP[row * 136 + 4 * (lane & 31)];
                    if (col < 600)       *(uint2*)&QP[(size_t)gr * 600 + col] = val;
                    else if (col < 1200) *(uint2*)&PK[(size_t)gr * 600 + (col - 600)] = val;
                    else                 *(uint2*)&V [(size_t)gr * 300 + (col - 1200)] = val;
                }
            }
        }
    }
    // pass 2: f32 skip destination (cols in [1500,1800)), row-half x col-half
    if (c0 + 128 > 1500) {
        #pragma unroll
        for (int hm = 0; hm < 2; hm++) {
            #pragma unroll
            for (int h = 0; h < 2; h++) {
                if (c0 + h * 64 + 63 < 1500) continue;   // block-uniform: no f32 cols here
                __syncthreads();
                if ((wave >> 1) == hm && (wave & 1) == h) {   // single writer wave
                    #pragma unroll
                    for (int j = 0; j < 4; j++) {
                        int colL = j * 16 + lq * 4;           // 0..63 within col half
                        int colb = c0 + h * 64 + colL;
                        if (colb < NREAL) {
                            float4 bb = *(const float4*)&bcat[colb];
                            #pragma unroll
                            for (int i = 0; i < 4; i++) {
                                int row = i * 16 + lr;        // local 0..63
                                f32x4 vv;
                                vv[0] = acc[j][i][0] + bb.x;
                                vv[1] = acc[j][i][1] + bb.y;
                                vv[2] = acc[j][i][2] + bb.z;
                                vv[3] = acc[j][i][3] + bb.w;
                                *(f32x4*)&EPf[row * 68 + colL] = vv;
                            }
                        }
                    }
                }
                __syncthreads();
                #pragma unroll
                for (int rep = 0; rep < 16; rep++) {
                    int row = wave * 16 + rep;               // local 0..63
                    int gr = r0 + hm * 64 + row;
                    int col = c0 + h * 64 + lane;
                    if (gr < M && col >= 1500 && col < NREAL)
                        Ot[(size_t)gr * 300 + (col - 1500)] = EPf[row * 68 + lane];
                }
            }
        }
    }
}

// ---------------- K3: scatter U qe8 (both post-gemm, independent) ----------------
__global__ __launch_bounds__(256) void k3_scatter_qe8(
    const int* __restrict__ ei, const float* __restrict__ ea,
    int* __restrict__ cur,
    int2* __restrict__ esd, float* __restrict__ eas, int E, int ebk,
    const bf16* __restrict__ QP, const float* __restrict__ E8,
    float* __restrict__ QE8f, int N)
{
    __shared__ unsigned short Qs[64 * 302];     // qe8 staging (padded rows)
    const int bid = blockIdx.x;
    if (bid < ebk) {
        int e = bid * 256 + threadIdx.x;
        if (e < E) {
            int s = ei[e];
            int d = ei[E + e];
            float4 a = *(const float4*)&ea[(size_t)e * 4];
            int p = atomicAdd(&cur[d], 1);
            esd[p] = make_int2(s, d);
            *(float4*)&eas[(size_t)p * 4] = a;
        }
        return;
    }
    const int tid = threadIdx.x;
    const int n0 = (bid - ebk) * 64;
    const int nrows = min(64, N - n0);
    const int nu = nrows * 300;
    const uint* src = (const uint*)QP + (size_t)n0 * 300;
    for (int i = tid; i < nu; i += 256) {
        int rr = i / 300, cc = i - rr * 300;
        Qs[rr * 302 + cc] = (unsigned short)src[i];     // low 16b = Q bf16 bits
    }
    __syncthreads();
    const int w = tid >> 6, l = tid & 63;     // w = head, l = node
    if (l >= nrows) return;
    float acc[8] = {0.f,0.f,0.f,0.f,0.f,0.f,0.f,0.f};
    const int cb = 75 * w;
    for (int cc = 0; cc < 75; cc++) {
        int c = cb + cc;
        float qv = __uint_as_float(((uint)Qs[l * 302 + c]) << 16);
        #pragma unroll
        for (int s = 0; s < 8; s++) acc[s] += qv * E8[s * 300 + c];
    }
    float* out = QE8f + (size_t)(n0 + l) * 32;
    #pragma unroll
    for (int s = 0; s < 8; s++) out[s * 4 + w] = acc[s];
}

// ---------------- fused edge pass: alpha + softmax + PV accumulation ----------------
// Node-aligned wave partitioning: wave w owns nodes {n : off[n] in [w*per,(w+1)*per)}
// (binary search). All of a node's edges processed by one wave -> the per-edge
// softmax weights broadcast through LDS (ews) instead of an AW memory round-trip,
// and the PV accumulation (V gather + efc + macc) runs inline. Accumulation order
// = t ascending, identical to the previous edge_alpha+node_pv pair -> bit-identical.
__global__ __launch_bounds__(256) void edge_fused(
    const int2* __restrict__ esd, const float* __restrict__ eas,
    const bf16* __restrict__ QP, const bf16* __restrict__ PK,
    const bf16* __restrict__ V,
    const float* __restrict__ Mxy, const float* __restrict__ bgeo,
    const float* __restrict__ QE8f, const float* __restrict__ WclsT,
    const float* __restrict__ bcls, const float* __restrict__ E8,
    const int* __restrict__ off,
    float* __restrict__ Ot, int N, int E, int nwaves)
{
    __shared__ __align__(16) float red[4][18 * 68];
    __shared__ float res[4][20];
    __shared__ __align__(16) float ews[4][2][12];
    const int wv   = threadIdx.x >> 6;
    const int lane = threadIdx.x & 63;
    float* __restrict__ rw = red[wv];
    float* __restrict__ rs = res[wv];
    float* __restrict__ ew = &ews[wv][0][0];
    const int gw  = blockIdx.x * 4 + wv;
    const int per = (E + nwaves - 1) / nwaves;
    const int lo  = gw * per;
    if (lo >= E) return;
    const int hi = min(lo + per, E);
    // node range: n0 = first n with off[n] >= lo; n1 = first n with off[n] >= hi
    int n0, n1;
    {
        int a = 0, b = N;
        while (a < b) { int m = (a + b) >> 1; if (off[m] < lo) a = m + 1; else b = m; }
        n0 = a; b = N;
        while (a < b) { int m = (a + b) >> 1; if (off[m] < hi) a = m + 1; else b = m; }
        n1 = a;
    }
    if (n0 >= n1) return;
    const bool ok4 = lane < 44;                 // c = lane+256 < 300

    float mx0[5], mx1[5], bg[5], wcl[5][5], e8r[8][5];
    #pragma unroll
    for (int r = 0; r < 4; r++) {               // r<4: c<256<300 always valid
        int c = lane + 64 * r;
        mx0[r] = Mxy[c]; mx1[r] = Mxy[300 + c]; bg[r] = bgeo[c];
        #pragma unroll
        for (int cl = 0; cl < 5; cl++) wcl[cl][r] = WclsT[cl * 300 + c];
        #pragma unroll
        for (int rr = 0; rr < 8; rr++) e8r[rr][r] = E8[rr * 300 + c];
    }
    {
        int c = lane + 256;
        mx0[4] = ok4 ? Mxy[c] : 0.f;
        mx1[4] = ok4 ? Mxy[300 + c] : 0.f;
        bg[4]  = ok4 ? bgeo[c] : 0.f;
        #pragma unroll
        for (int cl = 0; cl < 5; cl++) wcl[cl][4] = ok4 ? WclsT[cl * 300 + c] : 0.f;
        #pragma unroll
        for (int rr = 0; rr < 8; rr++) e8r[rr][4] = ok4 ? E8[rr * 300 + c] : 0.f;
    }
    float bc[5];
    #pragma unroll
    for (int cl = 0; cl < 5; cl++) bc[cl] = bcls[cl];
    const float isc = 0.11547005383792516f;     // 1/sqrt(75)

    const uint* QPu = (const uint*)QP;
    const uint* PKu = (const uint*)PK;
    float prt[18];

    auto compute = [&](const uint (&pk)[5], const float (&qv)[5], const float (&pib)[5],
                       float az, float aw_, int ub) {
        float tt[5], qk[5];
        #pragma unroll
        for (int r = 0; r < 5; r++) {
            float pj = bflo(pk[r]), kf = bfhi(pk[r]);
            float v = pib[r] + pj + az * mx0[r] + aw_ * mx1[r];
            // v pre-doubled (weights x2): tanh = 1 - 2/(1+exp(v)); saturates correctly
            tt[r] = fmaf(-2.f, __builtin_amdgcn_rcpf(1.f + __expf(v)), 1.f);
            qk[r] = qv[r] * kf;
        }
        #pragma unroll
        for (int cl = 0; cl < 5; cl++)
            prt[ub + cl] = tt[0]*wcl[cl][0] + tt[1]*wcl[cl][1] + tt[2]*wcl[cl][2]
                         + tt[3]*wcl[cl][3] + tt[4]*wcl[cl][4];
        float h0 = qk[0], h3 = qk[4], h1 = 0.f, h2 = 0.f;
        if (lane < 11) h0 += qk[1]; else h1 += qk[1];   // lane+64  < 75
        if (lane < 22) h1 += qk[2]; else h2 += qk[2];   // lane+128 < 150
        if (lane < 33) h2 += qk[3]; else h3 += qk[3];   // lane+192 < 225
        prt[ub+5] = h0; prt[ub+6] = h1; prt[ub+7] = h2; prt[ub+8] = h3;
    };

    for (int n = n0; n < n1; n++) {
        const int e0 = off[n], e1 = off[n + 1];
        if (e0 == e1) continue;
        // dst-row state (Q | Pi+bg), loaded once per node
        float qv[5], pib[5];
        {
            const uint* qr = QPu + (size_t)n * 300 + lane;
            #pragma unroll
            for (int r = 0; r < 4; r++) {
                uint uq = qr[64 * r];
                qv[r] = bflo(uq); pib[r] = bfhi(uq) + bg[r];
            }
            uint uq = ok4 ? qr[256] : 0u;
            qv[4] = bflo(uq); pib[4] = bfhi(uq) + bg[4];
        }
        const f32x4* qe = (const f32x4*)(QE8f + (size_t)n * 32);
        float macc[5] = {0.f, 0.f, 0.f, 0.f, 0.f};
        float den0 = 0.f, den1 = 0.f, den2 = 0.f, den3 = 0.f;

        for (int t = e0; t < e1; t += 2) {
            const int i0 = t;
            const bool has1 = (t + 1 < e1);
            const int i1 = has1 ? t + 1 : t;       // tail duplicates compute, skips accum
            const int s0 = esd[i0].x, s1 = esd[i1].x;
            const float4 a40 = *(const float4*)&eas[(size_t)4 * i0];
            const float4 a41 = *(const float4*)&eas[(size_t)4 * i1];

            // src-row gathers (interleaved Pj|Kf)
            uint pk0[5], pk1[5];
            const uint* p0r = PKu + (size_t)s0 * 300 + lane;
            const uint* p1r = PKu + (size_t)s1 * 300 + lane;
            #pragma unroll
            for (int r = 0; r < 4; r++) { pk0[r] = p0r[64 * r]; pk1[r] = p1r[64 * r]; }
            pk0[4] = ok4 ? p0r[256] : 0u;
            pk1[4] = ok4 ? p1r[256] : 0u;

            compute(pk0, qv, pib, a40.z, a40.w, 0);
            compute(pk1, qv, pib, a41.z, a41.w, 9);

            // transpose-reduce: 18 sums of 64 lane-partials each
            #pragma unroll
            for (int v = 0; v < 18; v++) rw[v * 68 + lane] = prt[v];
            #pragma unroll
            for (int i = 0; i < 5; i++) {
                int v = 4 * i + (lane >> 4);
                const f32x4 q4 = *(const f32x4*)&rw[v * 68 + (lane & 15) * 4];
                float s = (q4[0] + q4[1]) + (q4[2] + q4[3]);
                s += __shfl_xor(s, 1, 64);
                s += __shfl_xor(s, 2, 64);
                s += __shfl_xor(s, 4, 64);
                s += __shfl_xor(s, 8, 64);
                if ((lane & 15) == 0 && v < 18) rs[v] = s;
            }
            // epilogue per half-wave (u = lane>>5); broadcast weights via LDS
            {
                const int    u  = lane >> 5;
                const int    ub = u * 9;
                const float4 au = u ? a41 : a40;
                float lg0 = rs[ub+0] + bc[0], lg1 = rs[ub+1] + bc[1], lg2 = rs[ub+2] + bc[2];
                float lg3 = rs[ub+3] + bc[3], lg4 = rs[ub+4] + bc[4];
                float mxv = fmaxf(fmaxf(fmaxf(lg0, lg1), fmaxf(lg2, lg3)), lg4);
                float p0 = __expf(lg0 - mxv), p1 = __expf(lg1 - mxv), p2 = __expf(lg2 - mxv);
                float p3 = __expf(lg3 - mxv), p4 = __expf(lg4 - mxv);
                float pinv = __builtin_amdgcn_rcpf(p0 + p1 + p2 + p3 + p4);
                p0 *= pinv; p1 *= pinv; p2 *= pinv; p3 *= pinv; p4 *= pinv;
                float ct  = au.x > 0.f ? 1.f : 0.f;
                float cb_ = au.y < 0.f ? 1.f : 0.f;
                f32x4 addv = ct*qe[0] + cb_*qe[1] + p0*qe[2] + p1*qe[3]
                           + p2*qe[4] + p3*qe[5] + p4*qe[6] + qe[7];
                float ax0 = __expf((rs[ub+5] + addv[0]) * isc);
                float ax1 = __expf((rs[ub+6] + addv[1]) * isc);
                float ax2 = __expf((rs[ub+7] + addv[2]) * isc);
                float ax3 = __expf((rs[ub+8] + addv[3]) * isc);
                if ((lane & 31) == 0) {
                    float* ewp = ew + u * 12;
                    *(float4*)(ewp)     = make_float4(ax0, ax1, ax2, ax3);
                    *(float4*)(ewp + 4) = make_float4(ct, cb_, p0, p1);
                    *(float4*)(ewp + 8) = make_float4(p2, p3, p4, 0.f);
                }
            }
            // V gathers (deferred past reduction to limit register overlap)
            float vv0[5], vv1[5];
            {
                const bf16* v0r = V + (size_t)s0 * 300 + lane;
                const bf16* v1r = V + (size_t)s1 * 300 + lane;
                #pragma unroll
                for (int r = 0; r < 4; r++) {
                    vv0[r] = __bfloat162float(v0r[64 * r]);
                    vv1[r] = __bfloat162float(v1r[64 * r]);
                }
                vv0[4] = ok4 ? __bfloat162float(v0r[256]) : 0.f;
                vv1[4] = ok4 ? __bfloat162float(v1r[256]) : 0.f;
            }
            // accumulate edge 0 then (if real) edge 1 -- same order as node_pv
            #pragma unroll
            for (int u = 0; u < 2; u++) {
                if (u == 1 && !has1) break;        // wave-uniform
                const float* ewp = ew + u * 12;
                float4 ax = *(const float4*)(ewp);
                float4 wa = *(const float4*)(ewp + 4);
                float4 wb = *(const float4*)(ewp + 8);
                const float* vvp = u ? vv1 : vv0;
                #pragma unroll
                for (int r = 0; r < 5; r++) {
                    float efc = wa.x * e8r[0][r] + wa.y * e8r[1][r] + wa.z * e8r[2][r]
                              + wa.w * e8r[3][r] + wb.x * e8r[4][r] + wb.y * e8r[5][r]
                              + wb.z * e8r[6][r] + e8r[7][r];
                    float w = (r == 0) ? ax.x
                            : (r == 1) ? (lane < 11 ? ax.x : ax.y)
                            : (r == 2) ? (lane < 22 ? ax.y : ax.z)
                            : (r == 3) ? (lane < 33 ? ax.z : ax.w)
                            : ax.w;
                    macc[r] += w * (vvp[r] + efc);
                }
                den0 += ax.x; den1 += ax.y; den2 += ax.z; den3 += ax.w;
            }
        }

        const float rd0 = __builtin_amdgcn_rcpf(den0);
        const float rd1 = __builtin_amdgcn_rcpf(den1);
        const float rd2 = __builtin_amdgcn_rcpf(den2);
        const float rd3 = __builtin_amdgcn_rcpf(den3);
        const size_t nrow = (size_t)n * 300;
        #pragma unroll
        for (int r = 0; r < 5; r++) {
            int c = lane + 64 * r;
            if (c < 300) {
                float rd = (r == 0) ? rd0
                         : (r == 1) ? (lane < 11 ? rd0 : rd1)
                         : (r == 2) ? (lane < 22 ? rd1 : rd2)
                         : (r == 3) ? (lane < 33 ? rd2 : rd3)
                         : rd3;
                Ot[nrow + c] += macc[r] * rd;
            }
        }
    }
}

// ---------------- launch ----------------
extern "C" void kernel_launch(void* const* d_in, const int* in_sizes, int n_in,
                              void* d_out, int out_size, void* d_ws, size_t ws_size,
                              hipStream_t stream)
{
    const float* x     = (const float*)d_in[0];
    const int*   ei    = (const int*)  d_in[1];
    const float* ea    = (const float*)d_in[2];
    const float* on    = (const float*)d_in[3];
    const float* Wq    = (const float*)d_in[4];
    const float* bq    = (const float*)d_in[5];
    const float* Wk    = (const float*)d_in[6];
    const float* bk    = (const float*)d_in[7];
    const float* Wv    = (const float*)d_in[8];
    const float* bv    = (const float*)d_in[9];
    const float* We    = (const float*)d_in[10];
    const float* Wn    = (const float*)d_in[11];
    const float* bn    = (const float*)d_in[12];
    const float* Wxy   = (const float*)d_in[13];
    const float* bxy   = (const float*)d_in[14];
    const float* Wloc  = (const float*)d_in[15];
    const float* bloc  = (const float*)d_in[16];
    const float* Wobj  = (const float*)d_in[17];
    const float* bobj  = (const float*)d_in[18];
    const float* Wfus  = (const float*)d_in[19];
    const float* bfus  = (const float*)d_in[20];
    const float* Wcls  = (const float*)d_in[21];
    const float* bcls  = (const float*)d_in[22];
    const float* Wskip = (const float*)d_in[23];
    const float* bskip = (const float*)d_in[24];
    const float* vocab = (const float*)d_in[25];

    const int N = in_sizes[0] / NDIM;
    const int E = in_sizes[1] / 2;

    // ---- workspace layout ----
    const size_t nodeElems = (size_t)N * 300;
    const size_t wcatElems = (size_t)NPAD * KPAD;
    const size_t xbElems   = (size_t)N * 320;
    // Xb (bf16 staging for gemm) is dead after gemm; overlay edge-phase floats
    // (AW region kept for layout stability; eas 4E, QE8f 32N live) into it.
    size_t xbBytes = xbElems * sizeof(bf16);
    const size_t ovlBytes = ((size_t)16 * E + (size_t)32 * N) * sizeof(float);
    if (ovlBytes > xbBytes) xbBytes = ovlBytes;

    const size_t f32Elems  = NREAL + 904 + 904 + 600 + 304 + 1504 + 304 + 304 + 2400 + 1504;
    const size_t intElems  = (size_t)N + (size_t)(N + 1) + (size_t)N
                           + (size_t)2 * E + 2048;
    size_t need = (5 * nodeElems + wcatElems) * sizeof(bf16) + xbBytes
                + f32Elems * sizeof(float) + intElems * sizeof(int);
    if (ws_size < need) return;

    bf16* wsh = (bf16*)d_ws;
    bf16* QPb   = wsh;                             // [N][600] interleaved Q|Pi
    bf16* PKb   = QPb + (size_t)2 * nodeElems;     // [N][600] interleaved Pj|Kf
    bf16* Vb    = PKb + (size_t)2 * nodeElems;     // [N][300]
    bf16* WcatT = Vb + nodeElems;
    bf16* Xb    = WcatT + wcatElems;
    // overlay region (valid only after gemm_mfma)
    float* AW   = (float*)Xb;                      // 12E (unused since R9 fusion)
    float* eas  = AW + (size_t)12 * E;             // 4E
    float* QE8f = eas + (size_t)4 * E;             // 32N
    float* ws = (float*)((char*)Xb + xbBytes);
    size_t o = 0;
    float* bcat  = ws + o; o += NREAL;
    float* Wn1   = ws + o; o += 904;
    float* Wn2   = ws + o; o += 904;
    float* Mxyb  = ws + o; o += 600;
    float* bgeo  = ws + o; o += 304;
    float* vf5   = ws + o; o += 1504;
    float* t0b   = ws + o; o += 304;
    float* t1b   = ws + o; o += 304;
    float* E8b   = ws + o; o += 2400;
    float* WclsT = ws + o; o += 1504;
    int* ip = (int*)(ws + o);
    int* deg    = ip;             ip += N;
    int* offb   = ip;             ip += N + 1;
    int* curb   = ip;             ip += N;
    int2* esd   = (int2*)ip;      ip += (size_t)2 * E;
    int* bsum   = ip;             ip += 1024;
    int* bexc   = ip;             ip += 1024;
    (void)n_in; (void)out_size; (void)AW;

    hipMemsetAsync(deg, 0, (size_t)N * sizeof(int), stream);

    const int ebk   = (E + 255) / 256;
    const int nconv = ((int)((size_t)N * 40) + 255) / 256;

    k1_pre_conv_hist<<<19 + nconv + ebk, 256, 0, stream>>>(
        Wn, bn, Wxy, bxy, Wloc, bloc, bobj, Wfus, vocab,
        Wn1, Wn2, Mxyb, bgeo, vf5, t0b, t1b,
        x, on, Xb, N, nconv, ei, deg, E);
    k2_pre2_pack<<<16 + (NPAD * KPAD + 255) / 256, 256, 0, stream>>>(
        We, bfus, vf5, t0b, t1b, Wcls, E8b, WclsT,
        Wq, Wk, Wv, Wskip, Wobj, Wn1, Wn2, bq, bk, bv, bskip, WcatT, bcat);

    const int nbl = (N + 1023) / 1024;
    scan_local<<<nbl, 1024, 0, stream>>>(deg, offb, bsum, N);
    scan_bsum<<<1, 1024, 0, stream>>>(bsum, bexc, nbl);
    scan_add<<<(N + 255) / 256, 256, 0, stream>>>(offb, curb, bexc, N, E);

    const int npan = (N + 127) / 128;
    gemm_mfma<<<npan * 15, 256, 0, stream>>>(Xb, WcatT, bcat,
                                             QPb, PKb, Vb, (float*)d_out, N, npan);

    // Xb dead from here; overlay buffers become live
    k3_scatter_qe8<<<ebk + (N + 63) / 64, 256, 0, stream>>>(
        ei, ea, curb, esd, eas, E, ebk, QPb, E8b, QE8f, N);

    const int eab = 2048;                 // 8192 waves, ~31 edges each, node-aligned
    edge_fused<<<eab, 256, 0, stream>>>(esd, eas, QPb, PKb, Vb,
                                        Mxyb, bgeo, QE8f, WclsT, bcls, E8b,
                                        offb, (float*)d_out, N, E, eab * 4);
}

// Round 10
// 645.201 us; speedup vs baseline: 1.0994x; 1.0994x over previous
//
#include <hip/hip_runtime.h>
#include <hip/hip_bf16.h>
#include <math.h>

#define NDIM 300
#define KPAD 320          // K padded: 300 x-dims + 3 normal dims + zeros
#define NREAL 1800
#define NPAD 1920         // 15 tiles of 128

typedef __hip_bfloat16 bf16;
typedef __attribute__((ext_vector_type(8))) short short8;   // 8 bf16 (4 VGPRs)
typedef __attribute__((ext_vector_type(4))) float f32x4;

__device__ __forceinline__ void gl_lds16(const void* g, void* l) {
    __builtin_amdgcn_global_load_lds(
        (const __attribute__((address_space(1))) void*)g,
        (__attribute__((address_space(3))) void*)l, 16, 0, 0);
}

__device__ __forceinline__ float bflo(uint u) { return __uint_as_float(u << 16); }
__device__ __forceinline__ float bfhi(uint u) { return __uint_as_float(u & 0xFFFF0000u); }

// ---------------- K1: small_pre U conv_xb U hist (independent parts) ----------------
// NOTE: Mxy and bgeo are pre-scaled by 2 (tanh argument doubling folded in).
__global__ void k1_pre_conv_hist(
    const float* __restrict__ Wn, const float* __restrict__ bn,
    const float* __restrict__ Wxy, const float* __restrict__ bxy,
    const float* __restrict__ Wloc, const float* __restrict__ bloc,
    const float* __restrict__ bobj,
    const float* __restrict__ Wfus,
    const float* __restrict__ vocab,
    float* __restrict__ Wn1, float* __restrict__ Wn2,
    float* __restrict__ Mxy, float* __restrict__ bgeo,
    float* __restrict__ vf5, float* __restrict__ t0, float* __restrict__ t1,
    const float* __restrict__ X, const float* __restrict__ Nrm,
    bf16* __restrict__ Xb, int M, int nconv,
    const int* __restrict__ ei, int* __restrict__ deg, int E)
{
    const int bid = blockIdx.x;
    if (bid < 19) {
        int i = bid * 256 + threadIdx.x;
        if (i < 900) {
            int r = i / 300, c = i % 300;
            float s = 0.f;
            for (int k = 0; k < 300; k++) s += Wn[r*300+k] * Wloc[(300+k)*300+c];
            Wn1[i] = s;
        } else if (i < 1800) {
            int j = i - 900; int r = j/300, c = j%300;
            float s = 0.f;
            for (int k = 0; k < 300; k++) s += Wn[r*300+k] * Wloc[(600+k)*300+c];
            Wn2[j] = s;
        } else if (i < 2400) {
            int j = i - 1800; int r = j/300, c = j%300;
            float s = 0.f;
            for (int k = 0; k < 300; k++) s += Wxy[r*300+k] * Wloc[k*300+c];
            Mxy[j] = 2.f * s;                           // x2 folded (tanh arg)
        } else if (i < 2700) {
            int c = i - 2400;
            float s = bloc[c] + bobj[c];
            for (int k = 0; k < 300; k++) s += bxy[k] * Wloc[k*300+c];
            for (int k = 0; k < 300; k++) s += bn[k] * (Wloc[(300+k)*300+c] + Wloc[(600+k)*300+c]);
            bgeo[c] = 2.f * s;                          // x2 folded (tanh arg)
        } else if (i < 4200) {
            int j = i - 2700; int p = j/300, c = j%300;
            float s = 0.f;
            for (int k = 0; k < 300; k++) s += vocab[(2+p)*300+k] * Wfus[(300+k)*300+c];
            vf5[j] = s;
        } else if (i < 4500) {
            int c = i - 4200;
            float s = 0.f;
            for (int k = 0; k < 300; k++) s += vocab[k] * Wfus[k*300+c];
            t0[c] = s;
        } else if (i < 4800) {
            int c = i - 4500;
            float s = 0.f;
            for (int k = 0; k < 300; k++) s += vocab[300+k] * Wfus[k*300+c];
            t1[c] = s;
        }
    } else if (bid < 19 + nconv) {
        int i = (bid - 19) * 256 + threadIdx.x;
        int row = i / 40, c8 = i % 40;
        if (row >= M) return;
        int c0 = c8 * 8;
        union { bf16 h[8]; short8 s; } u;
        #pragma unroll
        for (int t = 0; t < 8; t++) {
            int c = c0 + t;
            float v = 0.f;
            if (c < 300)      v = X[(size_t)row * 300 + c];
            else if (c < 303) v = Nrm[(size_t)row * 3 + (c - 300)];
            u.h[t] = __float2bfloat16(v);
        }
        *(short8*)&Xb[(size_t)row * 320 + c0] = u.s;
    } else {
        int e = (bid - 19 - nconv) * 256 + threadIdx.x;
        if (e < E) atomicAdd(&deg[ei[E + e]], 1);
    }
}

// ---------------- K2: small_pre2 U pack_w ----------------
// pack_w: OUTPUT COLUMNS PERMUTED so the gemm epilogue directly produces
// interleaved QP / PK layouts:
//   c' in [0,600):    even -> Q_{c'/2}   (seg0), odd -> Pi_{c'/2} (seg4, x2)
//   c' in [600,1200): even -> Pj         (seg5, x2), odd -> Kf    (seg1)
//   c' in [1200,1500): V (seg2);  [1500,1800): skip (seg3)
__global__ void k2_pre2_pack(
    const float* __restrict__ We, const float* __restrict__ bfus,
    const float* __restrict__ vf5, const float* __restrict__ t0, const float* __restrict__ t1,
    const float* __restrict__ Wcls,
    float* __restrict__ E8, float* __restrict__ WclsT,
    const float* __restrict__ Wq, const float* __restrict__ Wk,
    const float* __restrict__ Wv, const float* __restrict__ Wskip,
    const float* __restrict__ Wobj,
    const float* __restrict__ Wn1, const float* __restrict__ Wn2,
    const float* __restrict__ bq, const float* __restrict__ bk,
    const float* __restrict__ bv, const float* __restrict__ bskip,
    bf16* __restrict__ WcatT, float* __restrict__ bcat)
{
    const int bid = blockIdx.x;
    if (bid < 16) {
        int i = bid * 256 + threadIdx.x;
        if (i < 2400) {
            int r = i / 300, c = i % 300;
            const float* src;
            if (r == 0) src = t0;
            else if (r == 1) src = t1;
            else if (r == 7) src = bfus;
            else src = vf5 + (r - 2) * 300;
            float s = 0.f;
            for (int k = 0; k < 300; k++) s += src[k] * We[k*300+c];
            E8[i] = s;
        } else if (i < 3900) {
            int j = i - 2400; int cl = j / 300, c = j % 300;
            WclsT[cl * 300 + c] = Wcls[c * 5 + cl];
        }
    } else {
        int i = (bid - 16) * 256 + threadIdx.x;
        if (i < NREAL) {
            int c = i;
            float b = 0.f;
            if (c < 600)       { if (!(c & 1)) b = bq[c >> 1]; }
            else if (c < 1200) { int cc = c - 600; if (cc & 1) b = bk[cc >> 1]; }
            else if (c < 1500) b = bv[c - 1200];
            else               b = bskip[c - 1500];
            bcat[i] = b;
        }
        if (i < NPAD * KPAD) {
            int cp = i / KPAD, k = i % KPAD;
            float v = 0.f;
            if (cp < NREAL) {
                int seg, jj;
                if (cp < 600)       { jj = cp >> 1; seg = (cp & 1) ? 4 : 0; }
                else if (cp < 1200) { int cc = cp - 600; jj = cc >> 1; seg = (cc & 1) ? 1 : 5; }
                else if (cp < 1500) { jj = cp - 1200; seg = 2; }
                else                { jj = cp - 1500; seg = 3; }
                if (k < 300) {
                    switch (seg) {
                        case 0: v = Wq[k*300+jj]; break;
                        case 1: v = Wk[k*300+jj]; break;
                        case 2: v = Wv[k*300+jj]; break;
                        case 3: v = Wskip[k*300+jj]; break;
                        case 4: v = Wobj[k*300+jj] - Wobj[(300+k)*300+jj]; break;
                        default: v = Wobj[(300+k)*300+jj]; break;
                    }
                } else if (k < 303) {
                    if (seg == 4) v = Wn1[(k-300)*300+jj];
                    else if (seg == 5) v = Wn2[(k-300)*300+jj];
                }
                if (seg >= 4) v *= 2.f;                 // x2 folded (tanh arg)
            }
            WcatT[i] = __float2bfloat16(v);
        }
    }
}

// ---------------- scans ----------------
__global__ __launch_bounds__(1024) void scan_local(
    const int* __restrict__ deg, int* __restrict__ off, int* __restrict__ bsum, int N)
{
    __shared__ int buf[1024];
    int i = blockIdx.x * 1024 + threadIdx.x;
    int v = (i < N) ? deg[i] : 0;
    buf[threadIdx.x] = v;
    __syncthreads();
    #pragma unroll
    for (int ofs = 1; ofs < 1024; ofs <<= 1) {
        int t = (threadIdx.x >= ofs) ? buf[threadIdx.x - ofs] : 0;
        __syncthreads();
        buf[threadIdx.x] += t;
        __syncthreads();
    }
    if (i < N) off[i] = buf[threadIdx.x] - v;       // local exclusive
    if (threadIdx.x == 1023) bsum[blockIdx.x] = buf[1023];
}

__global__ __launch_bounds__(1024) void scan_bsum(
    const int* __restrict__ bsum, int* __restrict__ bexc, int nb)
{
    __shared__ int buf[1024];
    int v = (threadIdx.x < nb) ? bsum[threadIdx.x] : 0;
    buf[threadIdx.x] = v;
    __syncthreads();
    #pragma unroll
    for (int ofs = 1; ofs < 1024; ofs <<= 1) {
        int t = (threadIdx.x >= ofs) ? buf[threadIdx.x - ofs] : 0;
        __syncthreads();
        buf[threadIdx.x] += t;
        __syncthreads();
    }
    if (threadIdx.x < nb) bexc[threadIdx.x] = buf[threadIdx.x] - v;
}

__global__ void scan_add(int* __restrict__ off, int* __restrict__ cur,
                         const int* __restrict__ bexc, int N, int E)
{
    int i = blockIdx.x * blockDim.x + threadIdx.x;
    if (i < N) {
        int o = off[i] + bexc[i >> 10];
        off[i] = o; cur[i] = o;
    }
    if (i == 0) off[N] = E;
}

// ---------------- MFMA node-GEMM: [N,320]bf16 @ [320,1920]bf16 ----------------
// 1D grid, XCD-pinned panel mapping. Row-half LDS-transpose epilogue keeps total
// LDS = 32768 B. No forced min-occupancy (R6 lesson: launch_bounds(256,5) made the
// allocator spill the 64-VGPR accumulator -> +196 MB scratch traffic, 126->148us).
// Staging base pointers hoisted out of the K-loop to trim live registers.
__global__ __launch_bounds__(256) void gemm_mfma(
    const bf16* __restrict__ Xb,
    const bf16* __restrict__ Bt, const float* __restrict__ bcat,
    bf16* __restrict__ QP, bf16* __restrict__ PK, bf16* __restrict__ V,
    float* __restrict__ Ot, int M, int npan)
{
    __shared__ __align__(16) char smraw[32768];
    bf16*  Asb = (bf16*)smraw;                 // [2][128*32] staging
    bf16*  Bsb = (bf16*)(smraw + 16384);       // [2][128*32] staging
    bf16*  EP  = (bf16*)smraw;                 // [64][136] epilogue bf16 view (17408 B)
    float* EPf = (float*)smraw;                // [64][68]  epilogue f32 view  (17408 B)

    const int bid = blockIdx.x;
    int p, cx;
    {
        const int full = (npan >> 3) * 120;
        if (bid < full) {
            int g = bid / 120, r = bid - g * 120;
            p = (g << 3) + (r & 7); cx = r >> 3;
        } else {
            int r = bid - full;
            int tp = npan & 7;                  // >0 whenever this branch is taken
            p = (npan & ~7) + r % tp; cx = r / tp;
        }
    }
    const int r0 = p * 128;
    const int c0 = cx * 128;

    const int tid  = threadIdx.x;
    const int wave = tid >> 6;
    const int lane = tid & 63;
    const int wm = (wave >> 1) * 64;
    const int wn = (wave & 1) * 64;
    const int lr = lane & 15;
    const int lq = lane >> 4;

    f32x4 acc[4][4];
    #pragma unroll
    for (int j = 0; j < 4; j++)
        #pragma unroll
        for (int i = 0; i < 4; i++) acc[j][i] = (f32x4){0.f, 0.f, 0.f, 0.f};

    // hoisted per-thread staging sources (K-loop adds only kb)
    const bf16* aSrc[2];
    const bf16* bSrc[2];
    {
        const int bcol_l = lane >> 2;
        const int bkp    = (lane & 3) * 8;
        #pragma unroll
        for (int h = 0; h < 2; h++) {
            int t = h * 256 + wave * 64 + lane;
            int grow = min(r0 + (t >> 2), M - 1);
            aSrc[h] = Xb + (size_t)grow * 320 + (t & 3) * 8;
            bSrc[h] = Bt + (size_t)(c0 + wave * 32 + h * 16 + bcol_l) * KPAD + bkp;
        }
    }

    auto stage = [&](int buf, int kb) {
        #pragma unroll
        for (int h = 0; h < 2; h++) {
            int tbase = h * 256 + wave * 64;          // wave-uniform LDS base
            gl_lds16(aSrc[h] + kb, &Asb[buf * 4096 + tbase * 8]);
        }
        #pragma unroll
        for (int h = 0; h < 2; h++) {
            int cloc = wave * 32 + h * 16;
            gl_lds16(bSrc[h] + kb, &Bsb[buf * 4096 + cloc * 32]);
        }
    };

    stage(0, 0);
    #pragma unroll
    for (int it = 0; it < 10; it++) {
        __syncthreads();
        if (it < 9) stage((it + 1) & 1, (it + 1) * 32);
        const int b = it & 1;
        short8 af[4], bfr[4];
        #pragma unroll
        for (int i = 0; i < 4; i++)
            af[i] = *(const short8*)&Asb[b * 4096 + (wm + i * 16 + lr) * 32 + lq * 8];
        #pragma unroll
        for (int j = 0; j < 4; j++)
            bfr[j] = *(const short8*)&Bsb[b * 4096 + (wn + j * 16 + lr) * 32 + lq * 8];
        #pragma unroll
        for (int j = 0; j < 4; j++)
            #pragma unroll
            for (int i = 0; i < 4; i++)
                acc[j][i] = __builtin_amdgcn_mfma_f32_16x16x32_bf16(
                    bfr[j], af[i], acc[j][i], 0, 0, 0);
    }

    // ---------------- epilogue: row-half LDS transposes, coalesced stores ----------------
    // pass 1: bf16 destinations (cols < 1500), two 64-row halves
    if (c0 < 1500) {
        #pragma unroll
        for (int hm = 0; hm < 2; hm++) {
            __syncthreads();                    // LDS region free (staging or prev half)
            if ((wave >> 1) == hm) {            // this wave-pair owns rows hm*64..+63
                #pragma unroll
                for (int j = 0; j < 4; j++) {
                    int colL = wn + j * 16 + lq * 4;
                    float4 bb = *(const float4*)&bcat[c0 + colL];
                    #pragma unroll
                    for (int i = 0; i < 4; i++) {
                        int row = i * 16 + lr;          // local 0..63
                        union { bf16 h[4]; uint2 u2; } pk;
                        pk.h[0] = __float2bfloat16(acc[j][i][0] + bb.x);
                        pk.h[1] = __float2bfloat16(acc[j][i][1] + bb.y);
                        pk.h[2] = __float2bfloat16(acc[j][i][2] + bb.z);
                        pk.h[3] = __float2bfloat16(acc[j][i][3] + bb.w);
                        *(uint2*)&EP[row * 136 + colL] = pk.u2;
                    }
                }
            }
            __syncthreads();
            #pragma unroll
            for (int rep = 0; rep < 8; rep++) {
                int row = wave * 16 + rep * 2 + (lane >> 5);    // local 0..63
                int gr = r0 + hm * 64 + row;
                int col = c0 + 4 * (lane & 31);
                if (gr < M && col < 1500) {
                    uint2 val = *(const uint2*)&EP[row * 136 + 4 * (lane & 31)];
                    if (col < 600)       *(uint2*)&QP[(size_t)gr * 600 + col] = val;
                    else if (col < 1200) *(uint2*)&PK[(size_t)gr * 600 + (col - 600)] = val;
                    else                 *(uint2*)&V [(size_t)gr * 300 + (col - 1200)] = val;
                }
            }
        }
    }
    // pass 2: f32 skip destination (cols in [1500,1800)), row-half x col-half
    if (c0 + 128 > 1500) {
        #pragma unroll
        for (int hm = 0; hm < 2; hm++) {
            #pragma unroll
            for (int h = 0; h < 2; h++) {
                if (c0 + h * 64 + 63 < 1500) continue;   // block-uniform: no f32 cols here
                __syncthreads();
                if ((wave >> 1) == hm && (wave & 1) == h) {   // single writer wave
                    #pragma unroll
                    for (int j = 0; j < 4; j++) {
                        int colL = j * 16 + lq * 4;           // 0..63 within col half
                        int colb = c0 + h * 64 + colL;
                        if (colb < NREAL) {
                            float4 bb = *(const float4*)&bcat[colb];
                            #pragma unroll
                            for (int i = 0; i < 4; i++) {
                                int row = i * 16 + lr;        // local 0..63
                                f32x4 vv;
                                vv[0] = acc[j][i][0] + bb.x;
                                vv[1] = acc[j][i][1] + bb.y;
                                vv[2] = acc[j][i][2] + bb.z;
                                vv[3] = acc[j][i][3] + bb.w;
                                *(f32x4*)&EPf[row * 68 + colL] = vv;
                            }
                        }
                    }
                }
                __syncthreads();
                #pragma unroll
                for (int rep = 0; rep < 16; rep++) {
                    int row = wave * 16 + rep;               // local 0..63
                    int gr = r0 + hm * 64 + row;
                    int col = c0 + h * 64 + lane;
                    if (gr < M && col >= 1500 && col < NREAL)
                        Ot[(size_t)gr * 300 + (col - 1500)] = EPf[row * 68 + lane];
                }
            }
        }
    }
}

// ---------------- K3: scatter U qe8 (both post-gemm, independent) ----------------
__global__ __launch_bounds__(256) void k3_scatter_qe8(
    const int* __restrict__ ei, const float* __restrict__ ea,
    int* __restrict__ cur,
    int2* __restrict__ esd, float* __restrict__ eas, int E, int ebk,
    const bf16* __restrict__ QP, const float* __restrict__ E8,
    float* __restrict__ QE8f, int N)
{
    __shared__ unsigned short Qs[64 * 302];     // qe8 staging (padded rows)
    const int bid = blockIdx.x;
    if (bid < ebk) {
        int e = bid * 256 + threadIdx.x;
        if (e < E) {
            int s = ei[e];
            int d = ei[E + e];
            float4 a = *(const float4*)&ea[(size_t)e * 4];
            int p = atomicAdd(&cur[d], 1);
            esd[p] = make_int2(s, d);
            *(float4*)&eas[(size_t)p * 4] = a;
        }
        return;
    }
    const int tid = threadIdx.x;
    const int n0 = (bid - ebk) * 64;
    const int nrows = min(64, N - n0);
    const int nu = nrows * 300;
    const uint* src = (const uint*)QP + (size_t)n0 * 300;
    for (int i = tid; i < nu; i += 256) {
        int rr = i / 300, cc = i - rr * 300;
        Qs[rr * 302 + cc] = (unsigned short)src[i];     // low 16b = Q bf16 bits
    }
    __syncthreads();
    const int w = tid >> 6, l = tid & 63;     // w = head, l = node
    if (l >= nrows) return;
    float acc[8] = {0.f,0.f,0.f,0.f,0.f,0.f,0.f,0.f};
    const int cb = 75 * w;
    for (int cc = 0; cc < 75; cc++) {
        int c = cb + cc;
        float qv = __uint_as_float(((uint)Qs[l * 302 + c]) << 16);
        #pragma unroll
        for (int s = 0; s < 8; s++) acc[s] += qv * E8[s * 300 + c];
    }
    float* out = QE8f + (size_t)(n0 + l) * 32;
    #pragma unroll
    for (int s = 0; s < 8; s++) out[s * 4 + w] = acc[s];
}

// ---------------- pass 1: edge-parallel alpha/prob, LDS-transpose reduction ----------------
// interleaved uint gathers (Q|Pi and Pj|Kf share loads) + dst-row hoisting.
// R10: register software-pipeline -- prefetch pair t+2's esd/eas/PK rows at the
// top of pair t's body so the dependent gather chain hides under compute+reduce.
__global__ __launch_bounds__(256) void edge_alpha(
    const int2* __restrict__ esd, const float* __restrict__ eas,
    const bf16* __restrict__ QP, const bf16* __restrict__ PK,
    const float* __restrict__ Mxy, const float* __restrict__ bgeo,
    const float* __restrict__ QE8f, const float* __restrict__ WclsT,
    const float* __restrict__ bcls,
    float* __restrict__ AW,
    int E, int nwaves)
{
    __shared__ __align__(16) float red[4][20 * 68];
    __shared__ float res[4][20];
    const int wv   = threadIdx.x >> 6;
    const int lane = threadIdx.x & 63;
    float* __restrict__ rw = red[wv];
    float* __restrict__ rs = res[wv];
    const int gw  = blockIdx.x * 4 + wv;
    const int per = (E + nwaves - 1) / nwaves;
    const int t0  = gw * per;
    if (t0 >= E) return;
    const int t1 = min(t0 + per, E);
    const bool ok4 = lane < 44;                 // c = lane+256 < 300

    float mx0[5], mx1[5], bg[5], wcl[5][5];
    #pragma unroll
    for (int r = 0; r < 4; r++) {               // r<4: c<256<300 always valid
        int c = lane + 64 * r;
        mx0[r] = Mxy[c]; mx1[r] = Mxy[300 + c]; bg[r] = bgeo[c];
        #pragma unroll
        for (int cl = 0; cl < 5; cl++) wcl[cl][r] = WclsT[cl * 300 + c];
    }
    {
        int c = lane + 256;
        mx0[4] = ok4 ? Mxy[c] : 0.f;
        mx1[4] = ok4 ? Mxy[300 + c] : 0.f;
        bg[4]  = ok4 ? bgeo[c] : 0.f;
        #pragma unroll
        for (int cl = 0; cl < 5; cl++) wcl[cl][4] = ok4 ? WclsT[cl * 300 + c] : 0.f;
    }
    float bc[5];
    #pragma unroll
    for (int cl = 0; cl < 5; cl++) bc[cl] = bcls[cl];
    const float isc = 0.11547005383792516f;     // 1/sqrt(75)

    const uint* QPu = (const uint*)QP;
    const uint* PKu = (const uint*)PK;

    int prev_d = -1;
    float qv[5], pib[5];                        // persistent dst-row state (Q, Pi+bg)
    float prt[18];

    auto reload = [&](int dd) {
        const uint* qr = QPu + (size_t)dd * 300 + lane;
        #pragma unroll
        for (int r = 0; r < 4; r++) {
            uint uq = qr[64 * r];
            qv[r] = bflo(uq); pib[r] = bfhi(uq) + bg[r];
        }
        uint uq = ok4 ? qr[256] : 0u;
        qv[4] = bflo(uq); pib[4] = bfhi(uq) + bg[4];
    };
    auto compute = [&](const uint (&pk)[5], float az, float aw_, int ub) {
        float tt[5], qk[5];
        #pragma unroll
        for (int r = 0; r < 5; r++) {
            float pj = bflo(pk[r]), kf = bfhi(pk[r]);
            float v = pib[r] + pj + az * mx0[r] + aw_ * mx1[r];
            // v pre-doubled (weights x2): tanh = 1 - 2/(1+exp(v)); saturates correctly
            tt[r] = fmaf(-2.f, __builtin_amdgcn_rcpf(1.f + __expf(v)), 1.f);
            qk[r] = qv[r] * kf;
        }
        #pragma unroll
        for (int cl = 0; cl < 5; cl++)
            prt[ub + cl] = tt[0]*wcl[cl][0] + tt[1]*wcl[cl][1] + tt[2]*wcl[cl][2]
                         + tt[3]*wcl[cl][3] + tt[4]*wcl[cl][4];
        float h0 = qk[0], h3 = qk[4], h1 = 0.f, h2 = 0.f;
        if (lane < 11) h0 += qk[1]; else h1 += qk[1];   // lane+64  < 75
        if (lane < 22) h1 += qk[2]; else h2 += qk[2];   // lane+128 < 150
        if (lane < 33) h2 += qk[3]; else h3 += qk[3];   // lane+192 < 225
        prt[ub+5] = h0; prt[ub+6] = h1; prt[ub+7] = h2; prt[ub+8] = h3;
    };
    auto loadPair = [&](int i0, int i1, int2 &s0, int2 &s1,
                        float4 &A0, float4 &A1, uint (&P0)[5], uint (&P1)[5]) {
        s0 = esd[i0]; s1 = esd[i1];
        A0 = *(const float4*)&eas[(size_t)4 * i0];
        A1 = *(const float4*)&eas[(size_t)4 * i1];
        const uint* p0r = PKu + (size_t)s0.x * 300 + lane;
        const uint* p1r = PKu + (size_t)s1.x * 300 + lane;
        #pragma unroll
        for (int r = 0; r < 4; r++) { P0[r] = p0r[64 * r]; P1[r] = p1r[64 * r]; }
        P0[4] = ok4 ? p0r[256] : 0u;
        P1[4] = ok4 ? p1r[256] : 0u;
    };

    // pipeline prologue: load first pair
    int2 sd0, sd1;
    float4 a40, a41;
    uint pk0[5], pk1[5];
    loadPair(t0, (t0 + 1 < t1) ? t0 + 1 : t0, sd0, sd1, a40, a41, pk0, pk1);

    for (int t = t0; t < t1; t += 2) {
        const int i0 = t;
        const int i1 = (t + 1 < t1) ? t + 1 : t;     // tail duplicates (same write)
        // take current pair into locals
        const int2 csd0 = sd0, csd1 = sd1;
        const float4 ca0 = a40, ca1 = a41;
        uint cpk0[5], cpk1[5];
        #pragma unroll
        for (int r = 0; r < 5; r++) { cpk0[r] = pk0[r]; cpk1[r] = pk1[r]; }
        // prefetch next pair (clamped indices; loads overlap the work below)
        {
            const int tn = t + 2;
            const int j0 = (tn < t1) ? tn : i0;
            const int j1 = (tn + 1 < t1) ? tn + 1 : j0;
            loadPair(j0, j1, sd0, sd1, a40, a41, pk0, pk1);
        }

        if (csd0.y != prev_d) reload(csd0.y);        // wave-uniform branch
        compute(cpk0, ca0.z, ca0.w, 0);
        if (csd1.y != csd0.y) reload(csd1.y);
        compute(cpk1, ca1.z, ca1.w, 9);
        prev_d = csd1.y;

        // transpose-reduce: 18 sums of 64 lane-partials each
        #pragma unroll
        for (int v = 0; v < 18; v++) rw[v * 68 + lane] = prt[v];
        #pragma unroll
        for (int i = 0; i < 5; i++) {
            int v = 4 * i + (lane >> 4);
            const f32x4 q4 = *(const f32x4*)&rw[v * 68 + (lane & 15) * 4];
            float s = (q4[0] + q4[1]) + (q4[2] + q4[3]);
            s += __shfl_xor(s, 1, 64);
            s += __shfl_xor(s, 2, 64);
            s += __shfl_xor(s, 4, 64);
            s += __shfl_xor(s, 8, 64);
            if ((lane & 15) == 0 && v < 18) rs[v] = s;
        }
        // epilogue: half-wave per edge (u = lane>>5)
        {
            const int    u  = lane >> 5;
            const int    ub = u * 9;
            const float4 au = u ? ca1 : ca0;
            const int    dd = u ? csd1.y : csd0.y;
            const int    tw = u ? i1 : i0;
            float lg0 = rs[ub+0] + bc[0], lg1 = rs[ub+1] + bc[1], lg2 = rs[ub+2] + bc[2];
            float lg3 = rs[ub+3] + bc[3], lg4 = rs[ub+4] + bc[4];
            float mxv = fmaxf(fmaxf(fmaxf(lg0, lg1), fmaxf(lg2, lg3)), lg4);
            float p0 = __expf(lg0 - mxv), p1 = __expf(lg1 - mxv), p2 = __expf(lg2 - mxv);
            float p3 = __expf(lg3 - mxv), p4 = __expf(lg4 - mxv);
            float pinv = __builtin_amdgcn_rcpf(p0 + p1 + p2 + p3 + p4);
            p0 *= pinv; p1 *= pinv; p2 *= pinv; p3 *= pinv; p4 *= pinv;
            float ct  = au.x > 0.f ? 1.f : 0.f;
            float cb_ = au.y < 0.f ? 1.f : 0.f;
            const f32x4* qe = (const f32x4*)(QE8f + (size_t)dd * 32);
            f32x4 addv = ct*qe[0] + cb_*qe[1] + p0*qe[2] + p1*qe[3]
                       + p2*qe[4] + p3*qe[5] + p4*qe[6] + qe[7];
            float ax0 = __expf((rs[ub+5] + addv[0]) * isc);
            float ax1 = __expf((rs[ub+6] + addv[1]) * isc);
            float ax2 = __expf((rs[ub+7] + addv[2]) * isc);
            float ax3 = __expf((rs[ub+8] + addv[3]) * isc);
            if ((lane & 31) == 0) {
                float* awp = AW + (size_t)12 * tw;
                *(float4*)(awp)     = make_float4(ax0, ax1, ax2, ax3);
                *(float4*)(awp + 4) = make_float4(ct, cb_, p0, p1);
                *(float4*)(awp + 8) = make_float4(p2, p3, p4, 0.f);
            }
        }
    }
}

// ---------------- pass 2: per-dst accumulation, 4-wide edge batching ----------------
__global__ __launch_bounds__(256) void node_pv(
    const int2* __restrict__ esd, const bf16* __restrict__ V,
    const float* __restrict__ E8, const float* __restrict__ AW,
    const int* __restrict__ off,
    float* __restrict__ Ot, int N)
{
    const int wid  = threadIdx.x >> 6;
    const int lane = threadIdx.x & 63;
    const int n = blockIdx.x * 4 + wid;
    if (n >= N) return;
    const int e0 = off[n], e1 = off[n + 1];
    if (e0 == e1) return;                       // out stays = skip
    const size_t nrow = (size_t)n * 300;
    const bool ok4 = lane < 44;

    float e8r[8][5];
    #pragma unroll
    for (int rr = 0; rr < 8; rr++) {
        #pragma unroll
        for (int r = 0; r < 4; r++) e8r[rr][r] = E8[rr * 300 + lane + 64 * r];
        e8r[rr][4] = ok4 ? E8[rr * 300 + lane + 256] : 0.f;
    }

    float macc[5] = {0.f, 0.f, 0.f, 0.f, 0.f};
    float den0 = 0.f, den1 = 0.f, den2 = 0.f, den3 = 0.f;

    int t = e0;
    for (; t + 4 <= e1; t += 4) {
        int s4[4];
        #pragma unroll
        for (int u = 0; u < 4; u++) s4[u] = esd[t + u].x;
        float vv[4][5];
        #pragma unroll
        for (int u = 0; u < 4; u++) {
            const bf16* vr = V + (size_t)s4[u] * 300 + lane;
            #pragma unroll
            for (int r = 0; r < 4; r++) vv[u][r] = __bfloat162float(vr[64 * r]);
            vv[u][4] = ok4 ? __bfloat162float(vr[256]) : 0.f;
        }
        #pragma unroll
        for (int u = 0; u < 4; u++) {
            const float* awp = AW + (size_t)12 * (t + u);
            float4 ax = *(const float4*)(awp);
            float4 wa = *(const float4*)(awp + 4);
            float4 wb = *(const float4*)(awp + 8);
            #pragma unroll
            for (int r = 0; r < 5; r++) {
                float efc = wa.x * e8r[0][r] + wa.y * e8r[1][r] + wa.z * e8r[2][r]
                          + wa.w * e8r[3][r] + wb.x * e8r[4][r] + wb.y * e8r[5][r]
                          + wb.z * e8r[6][r] + e8r[7][r];
                float w = (r == 0) ? ax.x
                        : (r == 1) ? (lane < 11 ? ax.x : ax.y)
                        : (r == 2) ? (lane < 22 ? ax.y : ax.z)
                        : (r == 3) ? (lane < 33 ? ax.z : ax.w)
                        : ax.w;
                macc[r] += w * (vv[u][r] + efc);
            }
            den0 += ax.x; den1 += ax.y; den2 += ax.z; den3 += ax.w;
        }
    }
    for (; t < e1; t++) {                       // tail 0-3 edges
        int s = esd[t].x;
        const float* awp = AW + (size_t)12 * t;
        float4 ax = *(const float4*)(awp);
        float4 wa = *(const float4*)(awp + 4);
        float4 wb = *(const float4*)(awp + 8);
        const bf16* vr = V + (size_t)s * 300 + lane;
        #pragma unroll
        for (int r = 0; r < 5; r++) {
            float vvs = (r < 4) ? __bfloat162float(vr[64 * r])
                                : (ok4 ? __bfloat162float(vr[256]) : 0.f);
            float efc = wa.x * e8r[0][r] + wa.y * e8r[1][r] + wa.z * e8r[2][r]
                      + wa.w * e8r[3][r] + wb.x * e8r[4][r] + wb.y * e8r[5][r]
                      + wb.z * e8r[6][r] + e8r[7][r];
            float w = (r == 0) ? ax.x
                    : (r == 1) ? (lane < 11 ? ax.x : ax.y)
                    : (r == 2) ? (lane < 22 ? ax.y : ax.z)
                    : (r == 3) ? (lane < 33 ? ax.z : ax.w)
                    : ax.w;
            macc[r] += w * (vvs + efc);
        }
        den0 += ax.x; den1 += ax.y; den2 += ax.z; den3 += ax.w;
    }

    const float rd0 = __builtin_amdgcn_rcpf(den0);
    const float rd1 = __builtin_amdgcn_rcpf(den1);
    const float rd2 = __builtin_amdgcn_rcpf(den2);
    const float rd3 = __builtin_amdgcn_rcpf(den3);
    #pragma unroll
    for (int r = 0; r < 5; r++) {
        int c = lane + 64 * r;
        if (c < 300) {
            float rd = (r == 0) ? rd0
                     : (r == 1) ? (lane < 11 ? rd0 : rd1)
                     : (r == 2) ? (lane < 22 ? rd1 : rd2)
                     : (r == 3) ? (lane < 33 ? rd2 : rd3)
                     : rd3;
            Ot[nrow + c] += macc[r] * rd;
        }
    }
}

// ---------------- launch ----------------
extern "C" void kernel_launch(void* const* d_in, const int* in_sizes, int n_in,
                              void* d_out, int out_size, void* d_ws, size_t ws_size,
                              hipStream_t stream)
{
    const float* x     = (const float*)d_in[0];
    const int*   ei    = (const int*)  d_in[1];
    const float* ea    = (const float*)d_in[2];
    const float* on    = (const float*)d_in[3];
    const float* Wq    = (const float*)d_in[4];
    const float* bq    = (const float*)d_in[5];
    const float* Wk    = (const float*)d_in[6];
    const float* bk    = (const float*)d_in[7];
    const float* Wv    = (const float*)d_in[8];
    const float* bv    = (const float*)d_in[9];
    const float* We    = (const float*)d_in[10];
    const float* Wn    = (const float*)d_in[11];
    const float* bn    = (const float*)d_in[12];
    const float* Wxy   = (const float*)d_in[13];
    const float* bxy   = (const float*)d_in[14];
    const float* Wloc  = (const float*)d_in[15];
    const float* bloc  = (const float*)d_in[16];
    const float* Wobj  = (const float*)d_in[17];
    const float* bobj  = (const float*)d_in[18];
    const float* Wfus  = (const float*)d_in[19];
    const float* bfus  = (const float*)d_in[20];
    const float* Wcls  = (const float*)d_in[21];
    const float* bcls  = (const float*)d_in[22];
    const float* Wskip = (const float*)d_in[23];
    const float* bskip = (const float*)d_in[24];
    const float* vocab = (const float*)d_in[25];

    const int N = in_sizes[0] / NDIM;
    const int E = in_sizes[1] / 2;

    // ---- workspace layout ----
    const size_t nodeElems = (size_t)N * 300;
    const size_t wcatElems = (size_t)NPAD * KPAD;
    const size_t xbElems   = (size_t)N * 320;
    // Xb (bf16 staging for gemm) is dead after gemm; overlay edge-phase floats
    // (AW 12E, eas 4E, QE8f 32N) into it.
    size_t xbBytes = xbElems * sizeof(bf16);
    const size_t ovlBytes = ((size_t)16 * E + (size_t)32 * N) * sizeof(float);
    if (ovlBytes > xbBytes) xbBytes = ovlBytes;

    const size_t f32Elems  = NREAL + 904 + 904 + 600 + 304 + 1504 + 304 + 304 + 2400 + 1504;
    const size_t intElems  = (size_t)N + (size_t)(N + 1) + (size_t)N
                           + (size_t)2 * E + 2048;
    size_t need = (5 * nodeElems + wcatElems) * sizeof(bf16) + xbBytes
                + f32Elems * sizeof(float) + intElems * sizeof(int);
    if (ws_size < need) return;

    bf16* wsh = (bf16*)d_ws;
    bf16* QPb   = wsh;                             // [N][600] interleaved Q|Pi
    bf16* PKb   = QPb + (size_t)2 * nodeElems;     // [N][600] interleaved Pj|Kf
    bf16* Vb    = PKb + (size_t)2 * nodeElems;     // [N][300]
    bf16* WcatT = Vb + nodeElems;
    bf16* Xb    = WcatT + wcatElems;
    // overlay region (valid only after gemm_mfma)
    float* AW   = (float*)Xb;                      // 12E
    float* eas  = AW + (size_t)12 * E;             // 4E
    float* QE8f = eas + (size_t)4 * E;             // 32N
    float* ws = (float*)((char*)Xb + xbBytes);
    size_t o = 0;
    float* bcat  = ws + o; o += NREAL;
    float* Wn1   = ws + o; o += 904;
    float* Wn2   = ws + o; o += 904;
    float* Mxyb  = ws + o; o += 600;
    float* bgeo  = ws + o; o += 304;
    float* vf5   = ws + o; o += 1504;
    float* t0b   = ws + o; o += 304;
    float* t1b   = ws + o; o += 304;
    float* E8b   = ws + o; o += 2400;
    float* WclsT = ws + o; o += 1504;
    int* ip = (int*)(ws + o);
    int* deg    = ip;             ip += N;
    int* offb   = ip;             ip += N + 1;
    int* curb   = ip;             ip += N;
    int2* esd   = (int2*)ip;      ip += (size_t)2 * E;
    int* bsum   = ip;             ip += 1024;
    int* bexc   = ip;             ip += 1024;
    (void)n_in; (void)out_size;

    hipMemsetAsync(deg, 0, (size_t)N * sizeof(int), stream);

    const int ebk   = (E + 255) / 256;
    const int nconv = ((int)((size_t)N * 40) + 255) / 256;

    k1_pre_conv_hist<<<19 + nconv + ebk, 256, 0, stream>>>(
        Wn, bn, Wxy, bxy, Wloc, bloc, bobj, Wfus, vocab,
        Wn1, Wn2, Mxyb, bgeo, vf5, t0b, t1b,
        x, on, Xb, N, nconv, ei, deg, E);
    k2_pre2_pack<<<16 + (NPAD * KPAD + 255) / 256, 256, 0, stream>>>(
        We, bfus, vf5, t0b, t1b, Wcls, E8b, WclsT,
        Wq, Wk, Wv, Wskip, Wobj, Wn1, Wn2, bq, bk, bv, bskip, WcatT, bcat);

    const int nbl = (N + 1023) / 1024;
    scan_local<<<nbl, 1024, 0, stream>>>(deg, offb, bsum, N);
    scan_bsum<<<1, 1024, 0, stream>>>(bsum, bexc, nbl);
    scan_add<<<(N + 255) / 256, 256, 0, stream>>>(offb, curb, bexc, N, E);

    const int npan = (N + 127) / 128;
    gemm_mfma<<<npan * 15, 256, 0, stream>>>(Xb, WcatT, bcat,
                                             QPb, PKb, Vb, (float*)d_out, N, npan);

    // Xb dead from here; overlay buffers become live
    k3_scatter_qe8<<<ebk + (N + 63) / 64, 256, 0, stream>>>(
        ei, ea, curb, esd, eas, E, ebk, QPb, E8b, QE8f, N);

    const int eab = 2048;                 // 8192 waves, ~31 sorted edges each
    edge_alpha<<<eab, 256, 0, stream>>>(esd, eas, QPb, PKb,
                                        Mxyb, bgeo, QE8f, WclsT, bcls,
                                        AW, E, eab * 4);

    const int nb = (N + 3) / 4;
    node_pv<<<nb, 256, 0, stream>>>(esd, Vb, E8b, AW,
                                    offb, (float*)d_out, N);
}

// Round 11
// 613.643 us; speedup vs baseline: 1.1559x; 1.0514x over previous
//
#include <hip/hip_runtime.h>
#include <hip/hip_bf16.h>
#include <math.h>

#define NDIM 300
#define KPAD 320          // K padded: 300 x-dims + 3 normal dims + zeros
#define NREAL 1800
#define NPAD 1920         // 15 tiles of 128

typedef __hip_bfloat16 bf16;
typedef __attribute__((ext_vector_type(8))) short short8;   // 8 bf16 (4 VGPRs)
typedef __attribute__((ext_vector_type(4))) float f32x4;

__device__ __forceinline__ void gl_lds16(const void* g, void* l) {
    __builtin_amdgcn_global_load_lds(
        (const __attribute__((address_space(1))) void*)g,
        (__attribute__((address_space(3))) void*)l, 16, 0, 0);
}

__device__ __forceinline__ float bflo(uint u) { return __uint_as_float(u << 16); }
__device__ __forceinline__ float bfhi(uint u) { return __uint_as_float(u & 0xFFFF0000u); }

// ---------------- K1: small_pre U conv_xb U hist (independent parts) ----------------
// NOTE: Mxy and bgeo are pre-scaled by 2 (tanh argument doubling folded in).
__global__ void k1_pre_conv_hist(
    const float* __restrict__ Wn, const float* __restrict__ bn,
    const float* __restrict__ Wxy, const float* __restrict__ bxy,
    const float* __restrict__ Wloc, const float* __restrict__ bloc,
    const float* __restrict__ bobj,
    const float* __restrict__ Wfus,
    const float* __restrict__ vocab,
    float* __restrict__ Wn1, float* __restrict__ Wn2,
    float* __restrict__ Mxy, float* __restrict__ bgeo,
    float* __restrict__ vf5, float* __restrict__ t0, float* __restrict__ t1,
    const float* __restrict__ X, const float* __restrict__ Nrm,
    bf16* __restrict__ Xb, int M, int nconv,
    const int* __restrict__ ei, int* __restrict__ deg, int E)
{
    const int bid = blockIdx.x;
    if (bid < 19) {
        int i = bid * 256 + threadIdx.x;
        if (i < 900) {
            int r = i / 300, c = i % 300;
            float s = 0.f;
            for (int k = 0; k < 300; k++) s += Wn[r*300+k] * Wloc[(300+k)*300+c];
            Wn1[i] = s;
        } else if (i < 1800) {
            int j = i - 900; int r = j/300, c = j%300;
            float s = 0.f;
            for (int k = 0; k < 300; k++) s += Wn[r*300+k] * Wloc[(600+k)*300+c];
            Wn2[j] = s;
        } else if (i < 2400) {
            int j = i - 1800; int r = j/300, c = j%300;
            float s = 0.f;
            for (int k = 0; k < 300; k++) s += Wxy[r*300+k] * Wloc[k*300+c];
            Mxy[j] = 2.f * s;                           // x2 folded (tanh arg)
        } else if (i < 2700) {
            int c = i - 2400;
            float s = bloc[c] + bobj[c];
            for (int k = 0; k < 300; k++) s += bxy[k] * Wloc[k*300+c];
            for (int k = 0; k < 300; k++) s += bn[k] * (Wloc[(300+k)*300+c] + Wloc[(600+k)*300+c]);
            bgeo[c] = 2.f * s;                          // x2 folded (tanh arg)
        } else if (i < 4200) {
            int j = i - 2700; int p = j/300, c = j%300;
            float s = 0.f;
            for (int k = 0; k < 300; k++) s += vocab[(2+p)*300+k] * Wfus[(300+k)*300+c];
            vf5[j] = s;
        } else if (i < 4500) {
            int c = i - 4200;
            float s = 0.f;
            for (int k = 0; k < 300; k++) s += vocab[k] * Wfus[k*300+c];
            t0[c] = s;
        } else if (i < 4800) {
            int c = i - 4500;
            float s = 0.f;
            for (int k = 0; k < 300; k++) s += vocab[300+k] * Wfus[k*300+c];
            t1[c] = s;
        }
    } else if (bid < 19 + nconv) {
        int i = (bid - 19) * 256 + threadIdx.x;
        int row = i / 40, c8 = i % 40;
        if (row >= M) return;
        int c0 = c8 * 8;
        union { bf16 h[8]; short8 s; } u;
        #pragma unroll
        for (int t = 0; t < 8; t++) {
            int c = c0 + t;
            float v = 0.f;
            if (c < 300)      v = X[(size_t)row * 300 + c];
            else if (c < 303) v = Nrm[(size_t)row * 3 + (c - 300)];
            u.h[t] = __float2bfloat16(v);
        }
        *(short8*)&Xb[(size_t)row * 320 + c0] = u.s;
    } else {
        int e = (bid - 19 - nconv) * 256 + threadIdx.x;
        if (e < E) atomicAdd(&deg[ei[E + e]], 1);
    }
}

// ---------------- K2: small_pre2 U pack_w ----------------
// pack_w: OUTPUT COLUMNS PERMUTED so the gemm epilogue directly produces
// interleaved QP / PK layouts:
//   c' in [0,600):    even -> Q_{c'/2}   (seg0), odd -> Pi_{c'/2} (seg4, x2)
//   c' in [600,1200): even -> Pj         (seg5, x2), odd -> Kf    (seg1)
//   c' in [1200,1500): V (seg2);  [1500,1800): skip (seg3)
__global__ void k2_pre2_pack(
    const float* __restrict__ We, const float* __restrict__ bfus,
    const float* __restrict__ vf5, const float* __restrict__ t0, const float* __restrict__ t1,
    const float* __restrict__ Wcls,
    float* __restrict__ E8, float* __restrict__ WclsT,
    const float* __restrict__ Wq, const float* __restrict__ Wk,
    const float* __restrict__ Wv, const float* __restrict__ Wskip,
    const float* __restrict__ Wobj,
    const float* __restrict__ Wn1, const float* __restrict__ Wn2,
    const float* __restrict__ bq, const float* __restrict__ bk,
    const float* __restrict__ bv, const float* __restrict__ bskip,
    bf16* __restrict__ WcatT, float* __restrict__ bcat)
{
    const int bid = blockIdx.x;
    if (bid < 16) {
        int i = bid * 256 + threadIdx.x;
        if (i < 2400) {
            int r = i / 300, c = i % 300;
            const float* src;
            if (r == 0) src = t0;
            else if (r == 1) src = t1;
            else if (r == 7) src = bfus;
            else src = vf5 + (r - 2) * 300;
            float s = 0.f;
            for (int k = 0; k < 300; k++) s += src[k] * We[k*300+c];
            E8[i] = s;
        } else if (i < 3900) {
            int j = i - 2400; int cl = j / 300, c = j % 300;
            WclsT[cl * 300 + c] = Wcls[c * 5 + cl];
        }
    } else {
        int i = (bid - 16) * 256 + threadIdx.x;
        if (i < NREAL) {
            int c = i;
            float b = 0.f;
            if (c < 600)       { if (!(c & 1)) b = bq[c >> 1]; }
            else if (c < 1200) { int cc = c - 600; if (cc & 1) b = bk[cc >> 1]; }
            else if (c < 1500) b = bv[c - 1200];
            else               b = bskip[c - 1500];
            bcat[i] = b;
        }
        if (i < NPAD * KPAD) {
            int cp = i / KPAD, k = i % KPAD;
            float v = 0.f;
            if (cp < NREAL) {
                int seg, jj;
                if (cp < 600)       { jj = cp >> 1; seg = (cp & 1) ? 4 : 0; }
                else if (cp < 1200) { int cc = cp - 600; jj = cc >> 1; seg = (cc & 1) ? 1 : 5; }
                else if (cp < 1500) { jj = cp - 1200; seg = 2; }
                else                { jj = cp - 1500; seg = 3; }
                if (k < 300) {
                    switch (seg) {
                        case 0: v = Wq[k*300+jj]; break;
                        case 1: v = Wk[k*300+jj]; break;
                        case 2: v = Wv[k*300+jj]; break;
                        case 3: v = Wskip[k*300+jj]; break;
                        case 4: v = Wobj[k*300+jj] - Wobj[(300+k)*300+jj]; break;
                        default: v = Wobj[(300+k)*300+jj]; break;
                    }
                } else if (k < 303) {
                    if (seg == 4) v = Wn1[(k-300)*300+jj];
                    else if (seg == 5) v = Wn2[(k-300)*300+jj];
                }
                if (seg >= 4) v *= 2.f;                 // x2 folded (tanh arg)
            }
            WcatT[i] = __float2bfloat16(v);
        }
    }
}

// ---------------- scans ----------------
__global__ __launch_bounds__(1024) void scan_local(
    const int* __restrict__ deg, int* __restrict__ off, int* __restrict__ bsum, int N)
{
    __shared__ int buf[1024];
    int i = blockIdx.x * 1024 + threadIdx.x;
    int v = (i < N) ? deg[i] : 0;
    buf[threadIdx.x] = v;
    __syncthreads();
    #pragma unroll
    for (int ofs = 1; ofs < 1024; ofs <<= 1) {
        int t = (threadIdx.x >= ofs) ? buf[threadIdx.x - ofs] : 0;
        __syncthreads();
        buf[threadIdx.x] += t;
        __syncthreads();
    }
    if (i < N) off[i] = buf[threadIdx.x] - v;       // local exclusive
    if (threadIdx.x == 1023) bsum[blockIdx.x] = buf[1023];
}

__global__ __launch_bounds__(1024) void scan_bsum(
    const int* __restrict__ bsum, int* __restrict__ bexc, int nb)
{
    __shared__ int buf[1024];
    int v = (threadIdx.x < nb) ? bsum[threadIdx.x] : 0;
    buf[threadIdx.x] = v;
    __syncthreads();
    #pragma unroll
    for (int ofs = 1; ofs < 1024; ofs <<= 1) {
        int t = (threadIdx.x >= ofs) ? buf[threadIdx.x - ofs] : 0;
        __syncthreads();
        buf[threadIdx.x] += t;
        __syncthreads();
    }
    if (threadIdx.x < nb) bexc[threadIdx.x] = buf[threadIdx.x] - v;
}

__global__ void scan_add(int* __restrict__ off, int* __restrict__ cur,
                         const int* __restrict__ bexc, int N, int E)
{
    int i = blockIdx.x * blockDim.x + threadIdx.x;
    if (i < N) {
        int o = off[i] + bexc[i >> 10];
        off[i] = o; cur[i] = o;
    }
    if (i == 0) off[N] = E;
}

// ---------------- MFMA node-GEMM: [N,320]bf16 @ [320,1920]bf16 ----------------
// 1D grid, XCD-pinned panel mapping. Row-half LDS-transpose epilogue keeps total
// LDS = 32768 B. No forced min-occupancy (R6 lesson: launch_bounds(256,5) made the
// allocator spill the 64-VGPR accumulator -> +196 MB scratch traffic, 126->148us).
// Staging base pointers hoisted out of the K-loop to trim live registers.
__global__ __launch_bounds__(256) void gemm_mfma(
    const bf16* __restrict__ Xb,
    const bf16* __restrict__ Bt, const float* __restrict__ bcat,
    bf16* __restrict__ QP, bf16* __restrict__ PK, bf16* __restrict__ V,
    float* __restrict__ Ot, int M, int npan)
{
    __shared__ __align__(16) char smraw[32768];
    bf16*  Asb = (bf16*)smraw;                 // [2][128*32] staging
    bf16*  Bsb = (bf16*)(smraw + 16384);       // [2][128*32] staging
    bf16*  EP  = (bf16*)smraw;                 // [64][136] epilogue bf16 view (17408 B)
    float* EPf = (float*)smraw;                // [64][68]  epilogue f32 view  (17408 B)

    const int bid = blockIdx.x;
    int p, cx;
    {
        const int full = (npan >> 3) * 120;
        if (bid < full) {
            int g = bid / 120, r = bid - g * 120;
            p = (g << 3) + (r & 7); cx = r >> 3;
        } else {
            int r = bid - full;
            int tp = npan & 7;                  // >0 whenever this branch is taken
            p = (npan & ~7) + r % tp; cx = r / tp;
        }
    }
    const int r0 = p * 128;
    const int c0 = cx * 128;

    const int tid  = threadIdx.x;
    const int wave = tid >> 6;
    const int lane = tid & 63;
    const int wm = (wave >> 1) * 64;
    const int wn = (wave & 1) * 64;
    const int lr = lane & 15;
    const int lq = lane >> 4;

    f32x4 acc[4][4];
    #pragma unroll
    for (int j = 0; j < 4; j++)
        #pragma unroll
        for (int i = 0; i < 4; i++) acc[j][i] = (f32x4){0.f, 0.f, 0.f, 0.f};

    // hoisted per-thread staging sources (K-loop adds only kb)
    const bf16* aSrc[2];
    const bf16* bSrc[2];
    {
        const int bcol_l = lane >> 2;
        const int bkp    = (lane & 3) * 8;
        #pragma unroll
        for (int h = 0; h < 2; h++) {
            int t = h * 256 + wave * 64 + lane;
            int grow = min(r0 + (t >> 2), M - 1);
            aSrc[h] = Xb + (size_t)grow * 320 + (t & 3) * 8;
            bSrc[h] = Bt + (size_t)(c0 + wave * 32 + h * 16 + bcol_l) * KPAD + bkp;
        }
    }

    auto stage = [&](int buf, int kb) {
        #pragma unroll
        for (int h = 0; h < 2; h++) {
            int tbase = h * 256 + wave * 64;          // wave-uniform LDS base
            gl_lds16(aSrc[h] + kb, &Asb[buf * 4096 + tbase * 8]);
        }
        #pragma unroll
        for (int h = 0; h < 2; h++) {
            int cloc = wave * 32 + h * 16;
            gl_lds16(bSrc[h] + kb, &Bsb[buf * 4096 + cloc * 32]);
        }
    };

    stage(0, 0);
    #pragma unroll
    for (int it = 0; it < 10; it++) {
        __syncthreads();
        if (it < 9) stage((it + 1) & 1, (it + 1) * 32);
        const int b = it & 1;
        short8 af[4], bfr[4];
        #pragma unroll
        for (int i = 0; i < 4; i++)
            af[i] = *(const short8*)&Asb[b * 4096 + (wm + i * 16 + lr) * 32 + lq * 8];
        #pragma unroll
        for (int j = 0; j < 4; j++)
            bfr[j] = *(const short8*)&Bsb[b * 4096 + (wn + j * 16 + lr) * 32 + lq * 8];
        #pragma unroll
        for (int j = 0; j < 4; j++)
            #pragma unroll
            for (int i = 0; i < 4; i++)
                acc[j][i] = __builtin_amdgcn_mfma_f32_16x16x32_bf16(
                    bfr[j], af[i], acc[j][i], 0, 0, 0);
    }

    // ---------------- epilogue: row-half LDS transposes, coalesced stores ----------------
    // pass 1: bf16 destinations (cols < 1500), two 64-row halves
    if (c0 < 1500) {
        #pragma unroll
        for (int hm = 0; hm < 2; hm++) {
            __syncthreads();                    // LDS region free (staging or prev half)
            if ((wave >> 1) == hm) {            // this wave-pair owns rows hm*64..+63
                #pragma unroll
                for (int j = 0; j < 4; j++) {
                    int colL = wn + j * 16 + lq * 4;
                    float4 bb = *(const float4*)&bcat[c0 + colL];
                    #pragma unroll
                    for (int i = 0; i < 4; i++) {
                        int row = i * 16 + lr;          // local 0..63
                        union { bf16 h[4]; uint2 u2; } pk;
                        pk.h[0] = __float2bfloat16(acc[j][i][0] + bb.x);
                        pk.h[1] = __float2bfloat16(acc[j][i][1] + bb.y);
                        pk.h[2] = __float2bfloat16(acc[j][i][2] + bb.z);
                        pk.h[3] = __float2bfloat16(acc[j][i][3] + bb.w);
                        *(uint2*)&EP[row * 136 + colL] = pk.u2;
                    }
                }
            }
            __syncthreads();
            #pragma unroll
            for (int rep = 0; rep < 8; rep++) {
                int row = wave * 16 + rep * 2 + (lane >> 5);    // local 0..63
                int gr = r0 + hm * 64 + row;
                int col = c0 + 4 * (lane & 31);
                if (gr < M && col < 1500) {
                    uint2 val = *(const uint2*)&EP[row * 136 + 4 * (lane & 31)];
                    if (col < 600)       *(uint2*)&QP[(size_t)gr * 600 + col] = val;
                    else if (col < 1200) *(uint2*)&PK[(size_t)gr * 600 + (col - 600)] = val;
                    else                 *(uint2*)&V [(size_t)gr * 300 + (col - 1200)] = val;
                }
            }
        }
    }
    // pass 2: f32 skip destination (cols in [1500,1800)), row-half x col-half
    if (c0 + 128 > 1500) {
        #pragma unroll
        for (int hm = 0; hm < 2; hm++) {
            #pragma unroll
            for (int h = 0; h < 2; h++) {
                if (c0 + h * 64 + 63 < 1500) continue;   // block-uniform: no f32 cols here
                __syncthreads();
                if ((wave >> 1) == hm && (wave & 1) == h) {   // single writer wave
                    #pragma unroll
                    for (int j = 0; j < 4; j++) {
                        int colL = j * 16 + lq * 4;           // 0..63 within col half
                        int colb = c0 + h * 64 + colL;
                        if (colb < NREAL) {
                            float4 bb = *(const float4*)&bcat[colb];
                            #pragma unroll
                            for (int i = 0; i < 4; i++) {
                                int row = i * 16 + lr;        // local 0..63
                                f32x4 vv;
                                vv[0] = acc[j][i][0] + bb.x;
                                vv[1] = acc[j][i][1] + bb.y;
                                vv[2] = acc[j][i][2] + bb.z;
                                vv[3] = acc[j][i][3] + bb.w;
                                *(f32x4*)&EPf[row * 68 + colL] = vv;
                            }
                        }
                    }
                }
                __syncthreads();
                #pragma unroll
                for (int rep = 0; rep < 16; rep++) {
                    int row = wave * 16 + rep;               // local 0..63
                    int gr = r0 + hm * 64 + row;
                    int col = c0 + h * 64 + lane;
                    if (gr < M && col >= 1500 && col < NREAL)
                        Ot[(size_t)gr * 300 + (col - 1500)] = EPf[row * 68 + lane];
                }
            }
        }
    }
}

// ---------------- K3: scatter U qe8 (both post-gemm, independent) ----------------
__global__ __launch_bounds__(256) void k3_scatter_qe8(
    const int* __restrict__ ei, const float* __restrict__ ea,
    int* __restrict__ cur,
    int2* __restrict__ esd, float* __restrict__ eas, int E, int ebk,
    const bf16* __restrict__ QP, const float* __restrict__ E8,
    float* __restrict__ QE8f, int N)
{
    __shared__ unsigned short Qs[64 * 302];     // qe8 staging (padded rows)
    const int bid = blockIdx.x;
    if (bid < ebk) {
        int e = bid * 256 + threadIdx.x;
        if (e < E) {
            int s = ei[e];
            int d = ei[E + e];
            float4 a = *(const float4*)&ea[(size_t)e * 4];
            int p = atomicAdd(&cur[d], 1);
            esd[p] = make_int2(s, d);
            *(float4*)&eas[(size_t)p * 4] = a;
        }
        return;
    }
    const int tid = threadIdx.x;
    const int n0 = (bid - ebk) * 64;
    const int nrows = min(64, N - n0);
    const int nu = nrows * 300;
    const uint* src = (const uint*)QP + (size_t)n0 * 300;
    for (int i = tid; i < nu; i += 256) {
        int rr = i / 300, cc = i - rr * 300;
        Qs[rr * 302 + cc] = (unsigned short)src[i];     // low 16b = Q bf16 bits
    }
    __syncthreads();
    const int w = tid >> 6, l = tid & 63;     // w = head, l = node
    if (l >= nrows) return;
    float acc[8] = {0.f,0.f,0.f,0.f,0.f,0.f,0.f,0.f};
    const int cb = 75 * w;
    for (int cc = 0; cc < 75; cc++) {
        int c = cb + cc;
        float qv = __uint_as_float(((uint)Qs[l * 302 + c]) << 16);
        #pragma unroll
        for (int s = 0; s < 8; s++) acc[s] += qv * E8[s * 300 + c];
    }
    float* out = QE8f + (size_t)(n0 + l) * 32;
    #pragma unroll
    for (int s = 0; s < 8; s++) out[s * 4 + w] = acc[s];
}

// ---------------- pass 1: edge-parallel alpha/prob, LDS-transpose reduction ----------------
// interleaved uint gathers (Q|Pi and Pj|Kf share loads) + dst-row hoisting.
// R11: red[] trimmed 20->18 rows (19904 B total LDS -> 8 blocks/CU, was 7);
// 5th reduce iteration runs exec-masked on half the wave (v=16,17 only) so no
// out-of-bounds reads. Register-neutral (R10 lesson: VGPR=64 is the 8-wave cliff).
__global__ __launch_bounds__(256) void edge_alpha(
    const int2* __restrict__ esd, const float* __restrict__ eas,
    const bf16* __restrict__ QP, const bf16* __restrict__ PK,
    const float* __restrict__ Mxy, const float* __restrict__ bgeo,
    const float* __restrict__ QE8f, const float* __restrict__ WclsT,
    const float* __restrict__ bcls,
    float* __restrict__ AW,
    int E, int nwaves)
{
    __shared__ __align__(16) float red[4][18 * 68];
    __shared__ float res[4][20];
    const int wv   = threadIdx.x >> 6;
    const int lane = threadIdx.x & 63;
    float* __restrict__ rw = red[wv];
    float* __restrict__ rs = res[wv];
    const int gw  = blockIdx.x * 4 + wv;
    const int per = (E + nwaves - 1) / nwaves;
    const int t0  = gw * per;
    if (t0 >= E) return;
    const int t1 = min(t0 + per, E);
    const bool ok4 = lane < 44;                 // c = lane+256 < 300

    float mx0[5], mx1[5], bg[5], wcl[5][5];
    #pragma unroll
    for (int r = 0; r < 4; r++) {               // r<4: c<256<300 always valid
        int c = lane + 64 * r;
        mx0[r] = Mxy[c]; mx1[r] = Mxy[300 + c]; bg[r] = bgeo[c];
        #pragma unroll
        for (int cl = 0; cl < 5; cl++) wcl[cl][r] = WclsT[cl * 300 + c];
    }
    {
        int c = lane + 256;
        mx0[4] = ok4 ? Mxy[c] : 0.f;
        mx1[4] = ok4 ? Mxy[300 + c] : 0.f;
        bg[4]  = ok4 ? bgeo[c] : 0.f;
        #pragma unroll
        for (int cl = 0; cl < 5; cl++) wcl[cl][4] = ok4 ? WclsT[cl * 300 + c] : 0.f;
    }
    float bc[5];
    #pragma unroll
    for (int cl = 0; cl < 5; cl++) bc[cl] = bcls[cl];
    const float isc = 0.11547005383792516f;     // 1/sqrt(75)

    const uint* QPu = (const uint*)QP;
    const uint* PKu = (const uint*)PK;

    int prev_d = -1;
    float qv[5], pib[5];                        // persistent dst-row state (Q, Pi+bg)
    float prt[18];

    auto reload = [&](int dd) {
        const uint* qr = QPu + (size_t)dd * 300 + lane;
        #pragma unroll
        for (int r = 0; r < 4; r++) {
            uint uq = qr[64 * r];
            qv[r] = bflo(uq); pib[r] = bfhi(uq) + bg[r];
        }
        uint uq = ok4 ? qr[256] : 0u;
        qv[4] = bflo(uq); pib[4] = bfhi(uq) + bg[4];
    };
    auto compute = [&](const uint (&pk)[5], float az, float aw_, int ub) {
        float tt[5], qk[5];
        #pragma unroll
        for (int r = 0; r < 5; r++) {
            float pj = bflo(pk[r]), kf = bfhi(pk[r]);
            float v = pib[r] + pj + az * mx0[r] + aw_ * mx1[r];
            // v pre-doubled (weights x2): tanh = 1 - 2/(1+exp(v)); saturates correctly
            tt[r] = fmaf(-2.f, __builtin_amdgcn_rcpf(1.f + __expf(v)), 1.f);
            qk[r] = qv[r] * kf;
        }
        #pragma unroll
        for (int cl = 0; cl < 5; cl++)
            prt[ub + cl] = tt[0]*wcl[cl][0] + tt[1]*wcl[cl][1] + tt[2]*wcl[cl][2]
                         + tt[3]*wcl[cl][3] + tt[4]*wcl[cl][4];
        float h0 = qk[0], h3 = qk[4], h1 = 0.f, h2 = 0.f;
        if (lane < 11) h0 += qk[1]; else h1 += qk[1];   // lane+64  < 75
        if (lane < 22) h1 += qk[2]; else h2 += qk[2];   // lane+128 < 150
        if (lane < 33) h2 += qk[3]; else h3 += qk[3];   // lane+192 < 225
        prt[ub+5] = h0; prt[ub+6] = h1; prt[ub+7] = h2; prt[ub+8] = h3;
    };

    for (int t = t0; t < t1; t += 2) {
        const int i0 = t;
        const int i1 = (t + 1 < t1) ? t + 1 : t;     // tail duplicates (same write)
        const int2 sd0 = esd[i0], sd1 = esd[i1];
        const float4 a40 = *(const float4*)&eas[(size_t)4 * i0];
        const float4 a41 = *(const float4*)&eas[(size_t)4 * i1];

        // src-row gathers for both edges (interleaved Pj|Kf)
        uint pk0[5], pk1[5];
        const uint* p0r = PKu + (size_t)sd0.x * 300 + lane;
        const uint* p1r = PKu + (size_t)sd1.x * 300 + lane;
        #pragma unroll
        for (int r = 0; r < 4; r++) { pk0[r] = p0r[64 * r]; pk1[r] = p1r[64 * r]; }
        pk0[4] = ok4 ? p0r[256] : 0u;
        pk1[4] = ok4 ? p1r[256] : 0u;

        if (sd0.y != prev_d) reload(sd0.y);          // wave-uniform branch
        compute(pk0, a40.z, a40.w, 0);
        if (sd1.y != sd0.y) reload(sd1.y);
        compute(pk1, a41.z, a41.w, 9);
        prev_d = sd1.y;

        // transpose-reduce: 18 sums of 64 lane-partials each
        #pragma unroll
        for (int v = 0; v < 18; v++) rw[v * 68 + lane] = prt[v];
        #pragma unroll
        for (int i = 0; i < 4; i++) {               // v = 0..15, all in-bounds
            int v = 4 * i + (lane >> 4);
            const f32x4 q4 = *(const f32x4*)&rw[v * 68 + (lane & 15) * 4];
            float s = (q4[0] + q4[1]) + (q4[2] + q4[3]);
            s += __shfl_xor(s, 1, 64);
            s += __shfl_xor(s, 2, 64);
            s += __shfl_xor(s, 4, 64);
            s += __shfl_xor(s, 8, 64);
            if ((lane & 15) == 0) rs[v] = s;
        }
        if ((lane >> 4) < 2) {                      // v = 16,17 (exec-masked tail)
            int v = 16 + (lane >> 4);
            const f32x4 q4 = *(const f32x4*)&rw[v * 68 + (lane & 15) * 4];
            float s = (q4[0] + q4[1]) + (q4[2] + q4[3]);
            s += __shfl_xor(s, 1, 64);              // exchanges stay within active 16-lane groups
            s += __shfl_xor(s, 2, 64);
            s += __shfl_xor(s, 4, 64);
            s += __shfl_xor(s, 8, 64);
            if ((lane & 15) == 0) rs[v] = s;
        }
        // epilogue: half-wave per edge (u = lane>>5)
        {
            const int    u  = lane >> 5;
            const int    ub = u * 9;
            const float4 au = u ? a41 : a40;
            const int    dd = u ? sd1.y : sd0.y;
            const int    tw = u ? i1 : i0;
            float lg0 = rs[ub+0] + bc[0], lg1 = rs[ub+1] + bc[1], lg2 = rs[ub+2] + bc[2];
            float lg3 = rs[ub+3] + bc[3], lg4 = rs[ub+4] + bc[4];
            float mxv = fmaxf(fmaxf(fmaxf(lg0, lg1), fmaxf(lg2, lg3)), lg4);
            float p0 = __expf(lg0 - mxv), p1 = __expf(lg1 - mxv), p2 = __expf(lg2 - mxv);
            float p3 = __expf(lg3 - mxv), p4 = __expf(lg4 - mxv);
            float pinv = __builtin_amdgcn_rcpf(p0 + p1 + p2 + p3 + p4);
            p0 *= pinv; p1 *= pinv; p2 *= pinv; p3 *= pinv; p4 *= pinv;
            float ct  = au.x > 0.f ? 1.f : 0.f;
            float cb_ = au.y < 0.f ? 1.f : 0.f;
            const f32x4* qe = (const f32x4*)(QE8f + (size_t)dd * 32);
            f32x4 addv = ct*qe[0] + cb_*qe[1] + p0*qe[2] + p1*qe[3]
                       + p2*qe[4] + p3*qe[5] + p4*qe[6] + qe[7];
            float ax0 = __expf((rs[ub+5] + addv[0]) * isc);
            float ax1 = __expf((rs[ub+6] + addv[1]) * isc);
            float ax2 = __expf((rs[ub+7] + addv[2]) * isc);
            float ax3 = __expf((rs[ub+8] + addv[3]) * isc);
            if ((lane & 31) == 0) {
                float* awp = AW + (size_t)12 * tw;
                *(float4*)(awp)     = make_float4(ax0, ax1, ax2, ax3);
                *(float4*)(awp + 4) = make_float4(ct, cb_, p0, p1);
                *(float4*)(awp + 8) = make_float4(p2, p3, p4, 0.f);
            }
        }
    }
}

// ---------------- pass 2: per-dst accumulation, 4-wide edge batching ----------------
__global__ __launch_bounds__(256) void node_pv(
    const int2* __restrict__ esd, const bf16* __restrict__ V,
    const float* __restrict__ E8, const float* __restrict__ AW,
    const int* __restrict__ off,
    float* __restrict__ Ot, int N)
{
    const int wid  = threadIdx.x >> 6;
    const int lane = threadIdx.x & 63;
    const int n = blockIdx.x * 4 + wid;
    if (n >= N) return;
    const int e0 = off[n], e1 = off[n + 1];
    if (e0 == e1) return;                       // out stays = skip
    const size_t nrow = (size_t)n * 300;
    const bool ok4 = lane < 44;

    float e8r[8][5];
    #pragma unroll
    for (int rr = 0; rr < 8; rr++) {
        #pragma unroll
        for (int r = 0; r < 4; r++) e8r[rr][r] = E8[rr * 300 + lane + 64 * r];
        e8r[rr][4] = ok4 ? E8[rr * 300 + lane + 256] : 0.f;
    }

    float macc[5] = {0.f, 0.f, 0.f, 0.f, 0.f};
    float den0 = 0.f, den1 = 0.f, den2 = 0.f, den3 = 0.f;

    int t = e0;
    for (; t + 4 <= e1; t += 4) {
        int s4[4];
        #pragma unroll
        for (int u = 0; u < 4; u++) s4[u] = esd[t + u].x;
        float vv[4][5];
        #pragma unroll
        for (int u = 0; u < 4; u++) {
            const bf16* vr = V + (size_t)s4[u] * 300 + lane;
            #pragma unroll
            for (int r = 0; r < 4; r++) vv[u][r] = __bfloat162float(vr[64 * r]);
            vv[u][4] = ok4 ? __bfloat162float(vr[256]) : 0.f;
        }
        #pragma unroll
        for (int u = 0; u < 4; u++) {
            const float* awp = AW + (size_t)12 * (t + u);
            float4 ax = *(const float4*)(awp);
            float4 wa = *(const float4*)(awp + 4);
            float4 wb = *(const float4*)(awp + 8);
            #pragma unroll
            for (int r = 0; r < 5; r++) {
                float efc = wa.x * e8r[0][r] + wa.y * e8r[1][r] + wa.z * e8r[2][r]
                          + wa.w * e8r[3][r] + wb.x * e8r[4][r] + wb.y * e8r[5][r]
                          + wb.z * e8r[6][r] + e8r[7][r];
                float w = (r == 0) ? ax.x
                        : (r == 1) ? (lane < 11 ? ax.x : ax.y)
                        : (r == 2) ? (lane < 22 ? ax.y : ax.z)
                        : (r == 3) ? (lane < 33 ? ax.z : ax.w)
                        : ax.w;
                macc[r] += w * (vv[u][r] + efc);
            }
            den0 += ax.x; den1 += ax.y; den2 += ax.z; den3 += ax.w;
        }
    }
    for (; t < e1; t++) {                       // tail 0-3 edges
        int s = esd[t].x;
        const float* awp = AW + (size_t)12 * t;
        float4 ax = *(const float4*)(awp);
        float4 wa = *(const float4*)(awp + 4);
        float4 wb = *(const float4*)(awp + 8);
        const bf16* vr = V + (size_t)s * 300 + lane;
        #pragma unroll
        for (int r = 0; r < 5; r++) {
            float vvs = (r < 4) ? __bfloat162float(vr[64 * r])
                                : (ok4 ? __bfloat162float(vr[256]) : 0.f);
            float efc = wa.x * e8r[0][r] + wa.y * e8r[1][r] + wa.z * e8r[2][r]
                      + wa.w * e8r[3][r] + wb.x * e8r[4][r] + wb.y * e8r[5][r]
                      + wb.z * e8r[6][r] + e8r[7][r];
            float w = (r == 0) ? ax.x
                    : (r == 1) ? (lane < 11 ? ax.x : ax.y)
                    : (r == 2) ? (lane < 22 ? ax.y : ax.z)
                    : (r == 3) ? (lane < 33 ? ax.z : ax.w)
                    : ax.w;
            macc[r] += w * (vvs + efc);
        }
        den0 += ax.x; den1 += ax.y; den2 += ax.z; den3 += ax.w;
    }

    const float rd0 = __builtin_amdgcn_rcpf(den0);
    const float rd1 = __builtin_amdgcn_rcpf(den1);
    const float rd2 = __builtin_amdgcn_rcpf(den2);
    const float rd3 = __builtin_amdgcn_rcpf(den3);
    #pragma unroll
    for (int r = 0; r < 5; r++) {
        int c = lane + 64 * r;
        if (c < 300) {
            float rd = (r == 0) ? rd0
                     : (r == 1) ? (lane < 11 ? rd0 : rd1)
                     : (r == 2) ? (lane < 22 ? rd1 : rd2)
                     : (r == 3) ? (lane < 33 ? rd2 : rd3)
                     : rd3;
            Ot[nrow + c] += macc[r] * rd;
        }
    }
}

// ---------------- launch ----------------
extern "C" void kernel_launch(void* const* d_in, const int* in_sizes, int n_in,
                              void* d_out, int out_size, void* d_ws, size_t ws_size,
                              hipStream_t stream)
{
    const float* x     = (const float*)d_in[0];
    const int*   ei    = (const int*)  d_in[1];
    const float* ea    = (const float*)d_in[2];
    const float* on    = (const float*)d_in[3];
    const float* Wq    = (const float*)d_in[4];
    const float* bq    = (const float*)d_in[5];
    const float* Wk    = (const float*)d_in[6];
    const float* bk    = (const float*)d_in[7];
    const float* Wv    = (const float*)d_in[8];
    const float* bv    = (const float*)d_in[9];
    const float* We    = (const float*)d_in[10];
    const float* Wn    = (const float*)d_in[11];
    const float* bn    = (const float*)d_in[12];
    const float* Wxy   = (const float*)d_in[13];
    const float* bxy   = (const float*)d_in[14];
    const float* Wloc  = (const float*)d_in[15];
    const float* bloc  = (const float*)d_in[16];
    const float* Wobj  = (const float*)d_in[17];
    const float* bobj  = (const float*)d_in[18];
    const float* Wfus  = (const float*)d_in[19];
    const float* bfus  = (const float*)d_in[20];
    const float* Wcls  = (const float*)d_in[21];
    const float* bcls  = (const float*)d_in[22];
    const float* Wskip = (const float*)d_in[23];
    const float* bskip = (const float*)d_in[24];
    const float* vocab = (const float*)d_in[25];

    const int N = in_sizes[0] / NDIM;
    const int E = in_sizes[1] / 2;

    // ---- workspace layout ----
    const size_t nodeElems = (size_t)N * 300;
    const size_t wcatElems = (size_t)NPAD * KPAD;
    const size_t xbElems   = (size_t)N * 320;
    // Xb (bf16 staging for gemm) is dead after gemm; overlay edge-phase floats
    // (AW 12E, eas 4E, QE8f 32N) into it.
    size_t xbBytes = xbElems * sizeof(bf16);
    const size_t ovlBytes = ((size_t)16 * E + (size_t)32 * N) * sizeof(float);
    if (ovlBytes > xbBytes) xbBytes = ovlBytes;

    const size_t f32Elems  = NREAL + 904 + 904 + 600 + 304 + 1504 + 304 + 304 + 2400 + 1504;
    const size_t intElems  = (size_t)N + (size_t)(N + 1) + (size_t)N
                           + (size_t)2 * E + 2048;
    size_t need = (5 * nodeElems + wcatElems) * sizeof(bf16) + xbBytes
                + f32Elems * sizeof(float) + intElems * sizeof(int);
    if (ws_size < need) return;

    bf16* wsh = (bf16*)d_ws;
    bf16* QPb   = wsh;                             // [N][600] interleaved Q|Pi
    bf16* PKb   = QPb + (size_t)2 * nodeElems;     // [N][600] interleaved Pj|Kf
    bf16* Vb    = PKb + (size_t)2 * nodeElems;     // [N][300]
    bf16* WcatT = Vb + nodeElems;
    bf16* Xb    = WcatT + wcatElems;
    // overlay region (valid only after gemm_mfma)
    float* AW   = (float*)Xb;                      // 12E
    float* eas  = AW + (size_t)12 * E;             // 4E
    float* QE8f = eas + (size_t)4 * E;             // 32N
    float* ws = (float*)((char*)Xb + xbBytes);
    size_t o = 0;
    float* bcat  = ws + o; o += NREAL;
    float* Wn1   = ws + o; o += 904;
    float* Wn2   = ws + o; o += 904;
    float* Mxyb  = ws + o; o += 600;
    float* bgeo  = ws + o; o += 304;
    float* vf5   = ws + o; o += 1504;
    float* t0b   = ws + o; o += 304;
    float* t1b   = ws + o; o += 304;
    float* E8b   = ws + o; o += 2400;
    float* WclsT = ws + o; o += 1504;
    int* ip = (int*)(ws + o);
    int* deg    = ip;             ip += N;
    int* offb   = ip;             ip += N + 1;
    int* curb   = ip;             ip += N;
    int2* esd   = (int2*)ip;      ip += (size_t)2 * E;
    int* bsum   = ip;             ip += 1024;
    int* bexc   = ip;             ip += 1024;
    (void)n_in; (void)out_size;

    hipMemsetAsync(deg, 0, (size_t)N * sizeof(int), stream);

    const int ebk   = (E + 255) / 256;
    const int nconv = ((int)((size_t)N * 40) + 255) / 256;

    k1_pre_conv_hist<<<19 + nconv + ebk, 256, 0, stream>>>(
        Wn, bn, Wxy, bxy, Wloc, bloc, bobj, Wfus, vocab,
        Wn1, Wn2, Mxyb, bgeo, vf5, t0b, t1b,
        x, on, Xb, N, nconv, ei, deg, E);
    k2_pre2_pack<<<16 + (NPAD * KPAD + 255) / 256, 256, 0, stream>>>(
        We, bfus, vf5, t0b, t1b, Wcls, E8b, WclsT,
        Wq, Wk, Wv, Wskip, Wobj, Wn1, Wn2, bq, bk, bv, bskip, WcatT, bcat);

    const int nbl = (N + 1023) / 1024;
    scan_local<<<nbl, 1024, 0, stream>>>(deg, offb, bsum, N);
    scan_bsum<<<1, 1024, 0, stream>>>(bsum, bexc, nbl);
    scan_add<<<(N + 255) / 256, 256, 0, stream>>>(offb, curb, bexc, N, E);

    const int npan = (N + 127) / 128;
    gemm_mfma<<<npan * 15, 256, 0, stream>>>(Xb, WcatT, bcat,
                                             QPb, PKb, Vb, (float*)d_out, N, npan);

    // Xb dead from here; overlay buffers become live
    k3_scatter_qe8<<<ebk + (N + 63) / 64, 256, 0, stream>>>(
        ei, ea, curb, esd, eas, E, ebk, QPb, E8b, QE8f, N);

    const int eab = 2048;                 // 8192 waves, ~31 sorted edges each
    edge_alpha<<<eab, 256, 0, stream>>>(esd, eas, QPb, PKb,
                                        Mxyb, bgeo, QE8f, WclsT, bcls,
                                        AW, E, eab * 4);

    const int nb = (N + 3) / 4;
    node_pv<<<nb, 256, 0, stream>>>(esd, Vb, E8b, AW,
                                    offb, (float*)d_out, N);
}